// Round 5
// baseline (269.957 us; speedup 1.0000x reference)
//
#include <hip/hip_runtime.h>

// CTC batch cost (Keras ctc_batch_cost, full lengths).
// B=64, T=2048, C=128 (blank=127), L=256, S=513.
//
// Round-17: MERGED FWD+BWD IN ONE WAVE (stall-filling A/B).
// Evidence: R12-R15 (4 structures, different instr counts/waits) all pin at
// ~240 cyc/step; R14's -25 instr/step diet was NEUTRAL -> not issue-bound;
// R16 (no LDS, 0 bank conflicts) was 75% SLOWER -> not LDS-conflict-bound.
// Remaining theory: a ~150 cyc/step stall, fixed per step, independent of
// scheduling (DPP serialization / boundary chain / wait machinery / clock).
// Test & exploit: run BOTH direction chains in ONE wave - two independent
// dataflows interleave so one chain's issue fills the other's stall.
//   - 64 blocks x 64 threads (1 wave). Dual LDS rings (F,B), 32KB each.
//   - Interleaved DMA: pair issue (8F + 8B per chunk), WAIT_VM(32)
//     never-drain (48 ops peak in flight, < 63 vmcnt limit).
//   - Per j: stepF, stepB, fillF, fillB; boundaries x2 every 4 steps.
//   - Final: alpha_1023 and c_1024 live in the SAME lane's registers ->
//     direct 9-FMA dot + 64-lane block-float logsumexp. No LDS handoff,
//     no __syncthreads.
// Numerics per chain bit-identical to R13 (101us, absmax 0.0): deferred-EPS,
// block-float linear mantissas, exponent renorm every 4 steps, DPP neighbor
// adoption (shr for F, shl for B).
// Outcome read: ~65-85us kernel => stall-filling works (fixed-stall theory
// confirmed). ~130-160us => issue-bound after all; revert to R13 next round.

#define B_ 64
#define T_ 2048
#define C_ 128
#define L_ 256
#define BLANK_ (C_ - 1)
#define EPSF 1e-7f
#define LN2F 0.69314718055994530942f
#define CH_ 16
#define SENT_ (-(1 << 28))    // "lane is all-zero" exponent sentinel

typedef __attribute__((address_space(1))) const void glob_cv;
typedef __attribute__((address_space(3))) void lds_v;

__device__ __forceinline__ void gl2lds16(const void* g, void* l) {
    __builtin_amdgcn_global_load_lds((glob_cv*)g, (lds_v*)l, 16, 0, 0);
}

#define WAIT_VM(n) asm volatile("s_waitcnt vmcnt(" #n ")" ::: "memory")

// lane l -> value of lane l-1; lane 0 -> 0. DPP ctrl 0x138 = wave_shr:1.
__device__ __forceinline__ float dpp_shr1_f(float x) {
    return __int_as_float(
        __builtin_amdgcn_update_dpp(0, __float_as_int(x), 0x138, 0xf, 0xf, false));
}
__device__ __forceinline__ int dpp_shr1_i(int x) {
    return __builtin_amdgcn_update_dpp(0, x, 0x138, 0xf, 0xf, false);
}
// lane l -> value of lane l+1; lane 63 -> 0. DPP ctrl 0x130 = wave_shl:1.
__device__ __forceinline__ float dpp_shl1_f(float x) {
    return __int_as_float(
        __builtin_amdgcn_update_dpp(0, __float_as_int(x), 0x130, 0xf, 0xf, false));
}
__device__ __forceinline__ int dpp_shl1_i(int x) {
    return __builtin_amdgcn_update_dpp(0, x, 0x130, 0xf, 0xf, false);
}

struct G { float pb, p1, p3, p5, p7; };  // RAW lds values (EPSF added at use)

__launch_bounds__(64, 1)
__global__ void ctc_loss_kernel(const int* __restrict__ y_true,
                                const float* __restrict__ y_pred,
                                float* __restrict__ out) {
    const int b = blockIdx.x;
    const int l = threadIdx.x;  // 0..63

    __shared__ float ringF[4][CH_ * C_];  // 4 bufs x 16 rows x 128 f32 = 32 KB
    __shared__ float ringB[4][CH_ * C_];  // 32 KB

    const int* __restrict__ lab = y_true + b * L_;
    const int4 lv = *(const int4*)(lab + 4 * l);   // labels 4l..4l+3
    const int e1 = lv.x, e3 = lv.y, e5 = lv.z, e7 = lv.w;
    const int em1 = (l > 0) ? lab[4 * l - 1] : -1;
    const float m1f = ((l > 0) && (e1 != em1)) ? 1.0f : 0.0f;  // skip gates
    const float m3f = (e3 != e1) ? 1.0f : 0.0f;
    const float m5f = (e5 != e3) ? 1.0f : 0.0f;
    const float m7f = (e7 != e5) ? 1.0f : 0.0f;
    const float m8f = (l == 63) ? 1.0f : 0.0f;     // state-512 coupling gate

    const float* __restrict__ base = y_pred + (size_t)b * (T_ * C_);

    // Column base pointers into each ring (gathers = vaddr + imm offset).
    const float* __restrict__ rbF = &ringF[0][0];
    const float* __restrict__ cBF = rbF + BLANK_;
    const float* __restrict__ c1F = rbF + e1;
    const float* __restrict__ c3F = rbF + e3;
    const float* __restrict__ c5F = rbF + e5;
    const float* __restrict__ c7F = rbF + e7;
    const float* __restrict__ rbB = &ringB[0][0];
    const float* __restrict__ cBB = rbB + BLANK_;
    const float* __restrict__ c1B = rbB + e1;
    const float* __restrict__ c3B = rbB + e3;
    const float* __restrict__ c5B = rbB + e5;
    const float* __restrict__ c7B = rbB + e7;

    auto issueF = [&](int t0, int buf) {
        const float* g = base + (size_t)t0 * C_ + 4 * l;  // lane*16B
#pragma unroll
        for (int i = 0; i < 8; ++i)
            gl2lds16(g + i * 256, &ringF[buf][i * 256]);
    };
    auto issueB = [&](int qc, int buf) {  // qc: 0 -> global chunk 127, ...
        const float* g = base + (size_t)(127 - qc) * CH_ * C_ + 4 * l;
#pragma unroll
        for (int i = 0; i < 8; ++i)
            gl2lds16(g + i * 256, &ringB[buf][i * 256]);
    };

    G gF[4], gB[4];  // lookahead-4 slots; slot index always compile-time
    auto fillF = [&](int slot, int off) {  // off = buf*2048 + row*128 (const)
        gF[slot].pb = cBF[off];
        gF[slot].p1 = c1F[off];
        gF[slot].p3 = c3F[off];
        gF[slot].p5 = c5F[off];
        gF[slot].p7 = c7F[off];
    };
    auto fillB = [&](int slot, int off) {
        gB[slot].pb = cBB[off];
        gB[slot].p1 = c1B[off];
        gB[slot].p3 = c3B[off];
        gB[slot].p5 = c5B[off];
        gB[slot].p7 = c7B[off];
    };

    // Two independent block-float recurrence states.
    float aF0 = 0.f, aF1 = 0.f, aF2 = 0.f, aF3 = 0.f, aF4 = 0.f,
          aF5 = 0.f, aF6 = 0.f, aF7 = 0.f, aF8 = 0.f;
    float aB0 = 0.f, aB1 = 0.f, aB2 = 0.f, aB3 = 0.f, aB4 = 0.f,
          aB5 = 0.f, aB6 = 0.f, aB7 = 0.f, aB8 = 0.f;
    int EF = SENT_, EB = SENT_;
    float upF = 1.0f, upB = 1.0f;  // 2^(E_nbr - E), fixed per 4-step window

    // ---------------- forward machinery ----------------
    auto stepF = [&](const G& q) {
        const float pb = q.pb + EPSF, p1 = q.p1 + EPSF, p3 = q.p3 + EPSF,
                    p5 = q.p5 + EPSF, p7 = q.p7 + EPSF;
        const float up = dpp_shr1_f(aF7) * upF;     // state 8l-1, rescaled
        const float n0 = (aF0 + up) * pb;
        const float n1 = fmaf(m1f, up, aF0 + aF1) * p1;
        const float n2 = (aF1 + aF2) * pb;
        const float n3 = fmaf(m3f, aF1, aF2 + aF3) * p3;
        const float n4 = (aF3 + aF4) * pb;
        const float n5 = fmaf(m5f, aF3, aF4 + aF5) * p5;
        const float n6 = (aF5 + aF6) * pb;
        const float n7 = fmaf(m7f, aF5, aF6 + aF7) * p7;
        const float n8 = fmaf(m8f, aF7, aF8) * pb;  // state 512
        aF0 = n0; aF1 = n1; aF2 = n2; aF3 = n3; aF4 = n4;
        aF5 = n5; aF6 = n6; aF7 = n7; aF8 = n8;
    };

    auto boundaryF = [&]() {
        float mx = fmaxf(fmaxf(fmaxf(aF0, aF1), fmaxf(aF2, aF3)),
                         fmaxf(fmaxf(aF4, aF5), fmaxf(aF6, aF7)));
        mx = fmaxf(mx, aF8);
        const bool z = (mx == 0.0f);
        const int e = (int)(__float_as_uint(mx) >> 23) - 127;
        const float s = z ? 1.0f : __uint_as_float((unsigned)(127 - e) << 23);
        aF0 *= s; aF1 *= s; aF2 *= s; aF3 *= s; aF4 *= s;
        aF5 *= s; aF6 *= s; aF7 *= s; aF8 *= s;
        EF = z ? SENT_ : (EF + e);
        int upE = dpp_shr1_i(EF);
        if (l == 0) upE = SENT_;
        if (EF == SENT_) EF = upE;          // adopt neighbor scale (exact)
        int d = upE - EF;
        d = min(max(d, -126), 120);
        upF = __uint_as_float((unsigned)(d + 127) << 23);
    };

    // ---------------- backward machinery ----------------
    auto stepB = [&](const G& q) {
        const float pb = q.pb + EPSF, p1 = q.p1 + EPSF, p3 = q.p3 + EPSF,
                    p5 = q.p5 + EPSF, p7 = q.p7 + EPSF;
        const float d0 = aB0 * pb, d1 = aB1 * p1, d2 = aB2 * pb,
                    d3 = aB3 * p3, d4 = aB4 * pb, d5 = aB5 * p5,
                    d6 = aB6 * pb, d7 = aB7 * p7, d8 = aB8 * pb;
        const float u = fmaf(m1f, d1, d0);          // exported to lane l-1
        const float dn = dpp_shl1_f(u) * upB;       // lane l+1's u, rescaled
        aB0 = d0 + d1;
        aB1 = fmaf(m3f, d3, d1 + d2);
        aB2 = d2 + d3;
        aB3 = fmaf(m5f, d5, d3 + d4);
        aB4 = d4 + d5;
        aB5 = fmaf(m7f, d7, d5 + d6);
        aB6 = d6 + d7;
        aB7 = fmaf(m8f, d8, d7 + dn);               // state 511 (+512 on l=63)
        aB8 = d8;                                   // state 512
    };

    auto boundaryB = [&]() {
        float mx = fmaxf(fmaxf(fmaxf(aB0, aB1), fmaxf(aB2, aB3)),
                         fmaxf(fmaxf(aB4, aB5), fmaxf(aB6, aB7)));
        mx = fmaxf(mx, aB8);
        const bool z = (mx == 0.0f);
        const int e = (int)(__float_as_uint(mx) >> 23) - 127;
        const float s = z ? 1.0f : __uint_as_float((unsigned)(127 - e) << 23);
        aB0 *= s; aB1 *= s; aB2 *= s; aB3 *= s; aB4 *= s;
        aB5 *= s; aB6 *= s; aB7 *= s; aB8 *= s;
        EB = z ? SENT_ : (EB + e);
        int upE = dpp_shl1_i(EB);           // neighbor is lane l+1
        if (l == 63) upE = SENT_;
        if (EB == SENT_) EB = upE;
        int d = upE - EB;
        d = min(max(d, -126), 120);
        upB = __uint_as_float((unsigned)(d + 127) << 23);
    };

    // Merged chunk body: per j, one F step + one B step + both refills.
    auto run_pair = [&](int bc, int bn, int jstartF, bool last) {
#pragma unroll
        for (int j = 0; j < CH_; ++j) {
            if (!(j == 0 && jstartF)) stepF(gF[j & 3]);  // folds at compile time
            stepB(gB[j & 3]);
            if (!last || j < 12) {
                const int offF = (j < 12) ? (bc * 2048 + (j + 4) * 128)
                                          : (bn * 2048 + (j - 12) * 128);
                fillF(j & 3, offF);
                const int offB = (j < 12) ? (bc * 2048 + (11 - j) * 128)
                                          : (bn * 2048 + (27 - j) * 128);
                fillB(j & 3, offB);
            }
            if ((j & 3) == 3) { boundaryF(); boundaryB(); }
        }
    };

    // ---- prologue: F/B chunk pairs 0,1,2 in flight (48 ops) ----
    issueF(0, 0);        issueB(0, 0);
    issueF(CH_, 1);      issueB(1, 1);
    issueF(2 * CH_, 2);  issueB(2, 2);
    WAIT_VM(32);                       // pair 0 landed; 1,2 in flight
    issueF(3 * CH_, 3);  issueB(3, 3); // 48 in flight

    // init F (t=0) and B (c_2048 = f)
    if (l == 0) { aF0 = rbF[BLANK_] + EPSF; aF1 = rbF[e1] + EPSF; EF = 0; }
    boundaryF();                       // seeds lane1's adoption of EF
    if (l == 63) { aB7 = 1.0f; aB8 = 1.0f; EB = 0; }
    boundaryB();                       // seeds lane62's adoption of EB
    fillF(1, 1 * 128); fillF(2, 2 * 128); fillF(3, 3 * 128); fillF(0, 4 * 128);
    fillB(0, 15 * 128); fillB(1, 14 * 128); fillB(2, 13 * 128); fillB(3, 12 * 128);

    // ---- chunk 0 (buf0): F steps t=1..15, B steps q=0..15 ----
    run_pair(0, 1, 1, false);

    // ---- chunks 1..60 in 15 groups of 4 (bufs 1,2,3,0) ----
#pragma unroll 1
    for (int m = 0; m < 15; ++m) {
        const int c = 4 * m + 1;
        WAIT_VM(32); issueF((c + 3) * CH_, 0); issueB(c + 3, 0); run_pair(1, 2, 0, false);
        WAIT_VM(32); issueF((c + 4) * CH_, 1); issueB(c + 4, 1); run_pair(2, 3, 0, false);
        WAIT_VM(32); issueF((c + 5) * CH_, 2); issueB(c + 5, 2); run_pair(3, 0, 0, false);
        WAIT_VM(32); issueF((c + 6) * CH_, 3); issueB(c + 6, 3); run_pair(0, 1, 0, false);
    }

    // ---- chunks 61 (buf1), 62 (buf2), 63 (buf3) ----
    WAIT_VM(32); run_pair(1, 2, 0, false);   // 62,63 in flight
    WAIT_VM(16); run_pair(2, 3, 0, false);   // 63 in flight
    WAIT_VM(0);  run_pair(3, 3, 0, true);    // all landed
    // aF* = alpha_1023 @ 2^EF;  aB* = c_1024 @ 2^EB  (same lane, same states)

    // ---- p = <alpha_1023, c_1024>: lane dot + 64-lane block-float LSE ----
    float sd = aF0 * aB0;
    sd = fmaf(aF1, aB1, sd);
    sd = fmaf(aF2, aB2, sd);
    sd = fmaf(aF3, aB3, sd);
    sd = fmaf(aF4, aB4, sd);
    sd = fmaf(aF5, aB5, sd);
    sd = fmaf(aF6, aB6, sd);
    sd = fmaf(aF7, aB7, sd);
    sd = fmaf(aF8, aB8, sd);
    const bool nz = (sd > 0.0f);
    int Es = nz ? (EF + EB) : SENT_;
    int M = Es;
#pragma unroll
    for (int o = 32; o; o >>= 1) M = max(M, __shfl_xor(M, o));
    int d = Es - M;
    d = max(d, -126);
    float val = nz ? sd * __uint_as_float((unsigned)(d + 127) << 23) : 0.0f;
#pragma unroll
    for (int o = 32; o; o >>= 1) val += __shfl_xor(val, o);
    if (l == 0) out[b] = -(__logf(val) + (float)M * LN2F);
}

extern "C" void kernel_launch(void* const* d_in, const int* in_sizes, int n_in,
                              void* d_out, int out_size, void* d_ws, size_t ws_size,
                              hipStream_t stream) {
    const int* y_true = (const int*)d_in[0];
    const float* y_pred = (const float*)d_in[1];
    float* out = (float*)d_out;
    ctc_loss_kernel<<<B_, 64, 0, stream>>>(y_true, y_pred, out);
}

// Round 7
// 184.603 us; speedup vs baseline: 1.4624x; 1.4624x over previous
//
#include <hip/hip_runtime.h>

// CTC batch cost (Keras ctc_batch_cost, full lengths).
// B=64, T=2048, C=128 (blank=127), L=256, S=513.
//
// Round-19: HAND-ASM INNER LOOP, build-fixed (symbolic-operand lookahead).
// R18's theory (R17: merged fwd+bwd in one wave ran at exactly 2x per-chain
// cost -> issue-throughput-bound; algorithm needs ~36 slots/step, compiler
// emits ~75) stands; R18 failed on macro expansion (comma-bearing register
// tuple args) and had a latent hazard (lookahead regs as bare clobbers are
// considered dead between asm blocks while 20 ds_reads are in flight).
// This round:
//  - 20 lookahead slots g0b..g37 and 10 temps t0..t9 are LOCAL VARIABLES
//    passed as named asm operands ([g0b]"+&v", [t0]"=&v"), referenced
//    %[g0b] etc with slot numbers spliced via #S -> registers persist
//    across asm blocks by liveness; early-clobber prevents input aliasing.
//  - 30 VALU/step hand schedule (deferred-EPS, DPP cross-lane with >=2
//    instr RAW separation, gated fmacs); 5 ds_read_b32/step with
//    compile-time offset: imms; s_waitcnt lgkmcnt(15) per step (R15's
//    proven counted discipline; ladder 15/10/5/0 in the last chunk);
//    34-instr block-float boundary every 4 steps.
// Structure/numerics IDENTICAL to R13 (101us, absmax 0.0): fwd/bwd split
// waves, 4-buf LDS rings, gl2lds16 DMA, WAIT_VM(8) never-drain, exponent
// renorm every 4 steps with DPP neighbor adoption, meet at t=1023/1024,
// 9-FMA dot + 64-lane block-float logsumexp.

#define B_ 64
#define T_ 2048
#define C_ 128
#define L_ 256
#define BLANK_ (C_ - 1)
#define EPSF 1e-7f
#define LN2F 0.69314718055994530942f
#define CH_ 16
#define SENT_ (-(1 << 28))    // "lane is all-zero" exponent sentinel

typedef __attribute__((address_space(1))) const void glob_cv;
typedef __attribute__((address_space(3))) void lds_v;
typedef __attribute__((address_space(3))) float lds_f;

__device__ __forceinline__ void gl2lds16(const void* g, void* l) {
    __builtin_amdgcn_global_load_lds((glob_cv*)g, (lds_v*)l, 16, 0, 0);
}

#define WAIT_VM(n) asm volatile("s_waitcnt vmcnt(" #n ")" ::: "memory")
#define DRAIN_LGKM() asm volatile("s_waitcnt lgkmcnt(0)" ::: "memory")

#define XS_(x) #x
#define XS(x) XS_(x)

// 5 gathers of one row into lookahead slot S (current buf / next buf).
#define FILLC(S, OFF) \
  "ds_read_b32 %[g" #S "b], %[cB] offset:" XS(OFF) "\n\t" \
  "ds_read_b32 %[g" #S "1], %[c1] offset:" XS(OFF) "\n\t" \
  "ds_read_b32 %[g" #S "3], %[c3] offset:" XS(OFF) "\n\t" \
  "ds_read_b32 %[g" #S "5], %[c5] offset:" XS(OFF) "\n\t" \
  "ds_read_b32 %[g" #S "7], %[c7] offset:" XS(OFF) "\n\t"
#define FILLN(S, OFF) \
  "ds_read_b32 %[g" #S "b], %[nB] offset:" XS(OFF) "\n\t" \
  "ds_read_b32 %[g" #S "1], %[n1] offset:" XS(OFF) "\n\t" \
  "ds_read_b32 %[g" #S "3], %[n3] offset:" XS(OFF) "\n\t" \
  "ds_read_b32 %[g" #S "5], %[n5] offset:" XS(OFF) "\n\t" \
  "ds_read_b32 %[g" #S "7], %[n7] offset:" XS(OFF) "\n\t"

// one forward step (consumes slot S). eps = 1e-7f bits 0x33d6bf95.
#define STEPF(S, WN, FILLS) \
  "s_waitcnt lgkmcnt(" XS(WN) ")\n\t" \
  "v_mov_b32 %[t0], 0\n\t" \
  "v_add_f32 %[t1], 0x33d6bf95, %[g" #S "b]\n\t" \
  "v_add_f32 %[t2], 0x33d6bf95, %[g" #S "1]\n\t" \
  "v_add_f32 %[t3], 0x33d6bf95, %[g" #S "3]\n\t" \
  "v_add_f32 %[t4], 0x33d6bf95, %[g" #S "5]\n\t" \
  "v_add_f32 %[t5], 0x33d6bf95, %[g" #S "7]\n\t" \
  "v_mov_b32_dpp %[t0], %[va7] wave_shr:1 row_mask:0xf bank_mask:0xf\n\t" \
  "v_mul_f32 %[t0], %[t0], %[ups]\n\t" \
  "v_add_f32 %[t6], %[va0], %[va1]\n\t" \
  "v_fmac_f32 %[t6], %[m1], %[t0]\n\t" \
  "v_add_f32 %[va0], %[va0], %[t0]\n\t" \
  "v_mul_f32 %[va0], %[va0], %[t1]\n\t" \
  "v_add_f32 %[t7], %[va1], %[va2]\n\t" \
  "v_add_f32 %[t8], %[va2], %[va3]\n\t" \
  "v_fmac_f32 %[t8], %[m3], %[va1]\n\t" \
  "v_mul_f32 %[va1], %[t6], %[t2]\n\t" \
  "v_mul_f32 %[va2], %[t7], %[t1]\n\t" \
  "v_add_f32 %[t6], %[va3], %[va4]\n\t" \
  "v_add_f32 %[t7], %[va4], %[va5]\n\t" \
  "v_fmac_f32 %[t7], %[m5], %[va3]\n\t" \
  "v_mul_f32 %[va3], %[t8], %[t3]\n\t" \
  "v_mul_f32 %[va4], %[t6], %[t1]\n\t" \
  "v_add_f32 %[t6], %[va5], %[va6]\n\t" \
  "v_add_f32 %[t8], %[va6], %[va7]\n\t" \
  "v_fmac_f32 %[t8], %[m7], %[va5]\n\t" \
  "v_mul_f32 %[va5], %[t7], %[t4]\n\t" \
  "v_mul_f32 %[va6], %[t6], %[t1]\n\t" \
  "v_fmac_f32 %[va8], %[m8], %[va7]\n\t" \
  "v_mul_f32 %[va7], %[t8], %[t5]\n\t" \
  "v_mul_f32 %[va8], %[va8], %[t1]\n\t" \
  FILLS

// one backward step (consumes slot S).
#define STEPB(S, WN, FILLS) \
  "s_waitcnt lgkmcnt(" XS(WN) ")\n\t" \
  "v_mov_b32 %[t0], 0\n\t" \
  "v_add_f32 %[t1], 0x33d6bf95, %[g" #S "b]\n\t" \
  "v_add_f32 %[t2], 0x33d6bf95, %[g" #S "1]\n\t" \
  "v_add_f32 %[t3], 0x33d6bf95, %[g" #S "3]\n\t" \
  "v_add_f32 %[t4], 0x33d6bf95, %[g" #S "5]\n\t" \
  "v_add_f32 %[t5], 0x33d6bf95, %[g" #S "7]\n\t" \
  "v_mul_f32 %[va0], %[va0], %[t1]\n\t" \
  "v_mul_f32 %[va1], %[va1], %[t2]\n\t" \
  "v_mov_b32 %[t6], %[va0]\n\t" \
  "v_fmac_f32 %[t6], %[m1], %[va1]\n\t" \
  "v_mul_f32 %[va2], %[va2], %[t1]\n\t" \
  "v_mul_f32 %[va3], %[va3], %[t3]\n\t" \
  "v_mul_f32 %[va4], %[va4], %[t1]\n\t" \
  "v_mov_b32_dpp %[t0], %[t6] wave_shl:1 row_mask:0xf bank_mask:0xf\n\t" \
  "v_mul_f32 %[t0], %[t0], %[ups]\n\t" \
  "v_mul_f32 %[va5], %[va5], %[t4]\n\t" \
  "v_mul_f32 %[va6], %[va6], %[t1]\n\t" \
  "v_mul_f32 %[va7], %[va7], %[t5]\n\t" \
  "v_mul_f32 %[va8], %[va8], %[t1]\n\t" \
  "v_add_f32 %[t7], %[va1], %[va2]\n\t" \
  "v_fmac_f32 %[t7], %[m3], %[va3]\n\t" \
  "v_add_f32 %[va0], %[va0], %[va1]\n\t" \
  "v_add_f32 %[t8], %[va3], %[va4]\n\t" \
  "v_fmac_f32 %[t8], %[m5], %[va5]\n\t" \
  "v_add_f32 %[va2], %[va2], %[va3]\n\t" \
  "v_add_f32 %[t9], %[va5], %[va6]\n\t" \
  "v_fmac_f32 %[t9], %[m7], %[va7]\n\t" \
  "v_add_f32 %[va4], %[va4], %[va5]\n\t" \
  "v_add_f32 %[va6], %[va6], %[va7]\n\t" \
  "v_add_f32 %[va7], %[va7], %[t0]\n\t" \
  "v_fmac_f32 %[va7], %[m8], %[va8]\n\t" \
  "v_mov_b32 %[va1], %[t7]\n\t" \
  "v_mov_b32 %[va3], %[t8]\n\t" \
  "v_mov_b32 %[va5], %[t9]\n\t" \
  FILLS

// block-float boundary: renorm to max, E update, DPP neighbor adoption.
#define BDY_HEAD \
  "v_max_f32 %[t1], %[va0], %[va1]\n\t" \
  "v_max_f32 %[t2], %[va2], %[va3]\n\t" \
  "v_max_f32 %[t3], %[va4], %[va5]\n\t" \
  "v_max_f32 %[t4], %[va6], %[va7]\n\t" \
  "v_max_f32 %[t1], %[t1], %[t2]\n\t" \
  "v_max_f32 %[t3], %[t3], %[t4]\n\t" \
  "v_max_f32 %[t1], %[t1], %[t3]\n\t" \
  "v_max_f32 %[t1], %[t1], %[va8]\n\t" \
  "v_cmp_ne_u32 vcc, 0, %[t1]\n\t" \
  "v_lshrrev_b32 %[t2], 23, %[t1]\n\t" \
  "v_sub_u32 %[t3], 0xfe, %[t2]\n\t" \
  "v_lshlrev_b32 %[t3], 23, %[t3]\n\t" \
  "v_cndmask_b32 %[t3], 1.0, %[t3], vcc\n\t" \
  "v_mul_f32 %[va0], %[va0], %[t3]\n\t" \
  "v_mul_f32 %[va1], %[va1], %[t3]\n\t" \
  "v_mul_f32 %[va2], %[va2], %[t3]\n\t" \
  "v_mul_f32 %[va3], %[va3], %[t3]\n\t" \
  "v_mul_f32 %[va4], %[va4], %[t3]\n\t" \
  "v_mul_f32 %[va5], %[va5], %[t3]\n\t" \
  "v_mul_f32 %[va6], %[va6], %[t3]\n\t" \
  "v_mul_f32 %[va7], %[va7], %[t3]\n\t" \
  "v_mul_f32 %[va8], %[va8], %[t3]\n\t" \
  "v_add_u32 %[t2], 0xffffff81, %[t2]\n\t" \
  "v_add_u32 %[t2], %[E], %[t2]\n\t" \
  "v_mov_b32 %[t4], 0xf0000000\n\t" \
  "v_cndmask_b32 %[E], %[t4], %[t2], vcc\n\t" \
  "v_mov_b32 %[t5], 0xf0000000\n\t" \
  "s_nop 1\n\t"
#define BDY_TAIL \
  "v_cmp_ne_u32 vcc, 0xf0000000, %[E]\n\t" \
  "v_cndmask_b32 %[E], %[t5], %[E], vcc\n\t" \
  "v_sub_u32 %[t6], %[t5], %[E]\n\t" \
  "v_max_i32 %[t6], 0xffffff82, %[t6]\n\t" \
  "v_min_i32 %[t6], 0x78, %[t6]\n\t" \
  "v_add_u32 %[t6], 0x7f, %[t6]\n\t" \
  "v_lshlrev_b32 %[ups], 23, %[t6]\n\t"
#define BDYF BDY_HEAD \
  "v_mov_b32_dpp %[t5], %[E] wave_shr:1 row_mask:0xf bank_mask:0xf\n\t" \
  BDY_TAIL
#define BDYB BDY_HEAD \
  "v_mov_b32_dpp %[t5], %[E] wave_shl:1 row_mask:0xf bank_mask:0xf\n\t" \
  BDY_TAIL

// ---- chunk quads (4 steps + boundary); offsets = row*512 bytes ----
#define FWD_Q1 STEPF(0,15,FILLC(0,2048)) STEPF(1,15,FILLC(1,2560)) \
               STEPF(2,15,FILLC(2,3072)) STEPF(3,15,FILLC(3,3584)) BDYF
#define FWD_Q2 STEPF(0,15,FILLC(0,4096)) STEPF(1,15,FILLC(1,4608)) \
               STEPF(2,15,FILLC(2,5120)) STEPF(3,15,FILLC(3,5632)) BDYF
#define FWD_Q3 STEPF(0,15,FILLC(0,6144)) STEPF(1,15,FILLC(1,6656)) \
               STEPF(2,15,FILLC(2,7168)) STEPF(3,15,FILLC(3,7680)) BDYF
#define FWD_Q4 STEPF(0,15,FILLN(0,0))    STEPF(1,15,FILLN(1,512)) \
               STEPF(2,15,FILLN(2,1024)) STEPF(3,15,FILLN(3,1536)) BDYF
#define FWD_FULL_BODY FWD_Q1 FWD_Q2 FWD_Q3 FWD_Q4
#define FWD_FIRST_BODY \
  FILLC(1,512) FILLC(2,1024) FILLC(3,1536) FILLC(0,2048) \
  STEPF(1,15,FILLC(1,2560)) STEPF(2,15,FILLC(2,3072)) \
  STEPF(3,15,FILLC(3,3584)) BDYF \
  FWD_Q2 FWD_Q3 FWD_Q4
#define FWD_LAST_BODY FWD_Q1 FWD_Q2 FWD_Q3 \
  STEPF(0,15,"") STEPF(1,10,"") STEPF(2,5,"") STEPF(3,0,"") BDYF

#define BWD_Q1 STEPB(0,15,FILLC(0,5632)) STEPB(1,15,FILLC(1,5120)) \
               STEPB(2,15,FILLC(2,4608)) STEPB(3,15,FILLC(3,4096)) BDYB
#define BWD_Q2 STEPB(0,15,FILLC(0,3584)) STEPB(1,15,FILLC(1,3072)) \
               STEPB(2,15,FILLC(2,2560)) STEPB(3,15,FILLC(3,2048)) BDYB
#define BWD_Q3 STEPB(0,15,FILLC(0,1536)) STEPB(1,15,FILLC(1,1024)) \
               STEPB(2,15,FILLC(2,512))  STEPB(3,15,FILLC(3,0))    BDYB
#define BWD_Q4 STEPB(0,15,FILLN(0,7680)) STEPB(1,15,FILLN(1,7168)) \
               STEPB(2,15,FILLN(2,6656)) STEPB(3,15,FILLN(3,6144)) BDYB
#define BWD_FULL_BODY BWD_Q1 BWD_Q2 BWD_Q3 BWD_Q4
#define BWD_FIRST_BODY \
  FILLC(0,7680) FILLC(1,7168) FILLC(2,6656) FILLC(3,6144) \
  BWD_FULL_BODY
#define BWD_LAST_BODY BWD_Q1 BWD_Q2 BWD_Q3 \
  STEPB(0,15,"") STEPB(1,10,"") STEPB(2,5,"") STEPB(3,0,"") BDYB

// All outputs early-clobber: written before the last input read.
#define ST_OUTS \
  [va0]"+&v"(a0),[va1]"+&v"(a1),[va2]"+&v"(a2),[va3]"+&v"(a3), \
  [va4]"+&v"(a4),[va5]"+&v"(a5),[va6]"+&v"(a6),[va7]"+&v"(a7), \
  [va8]"+&v"(a8),[E]"+&v"(E),[ups]"+&v"(ups), \
  [g0b]"+&v"(g0b),[g01]"+&v"(g01),[g03]"+&v"(g03),[g05]"+&v"(g05),[g07]"+&v"(g07), \
  [g1b]"+&v"(g1b),[g11]"+&v"(g11),[g13]"+&v"(g13),[g15]"+&v"(g15),[g17]"+&v"(g17), \
  [g2b]"+&v"(g2b),[g21]"+&v"(g21),[g23]"+&v"(g23),[g25]"+&v"(g25),[g27]"+&v"(g27), \
  [g3b]"+&v"(g3b),[g31]"+&v"(g31),[g33]"+&v"(g33),[g35]"+&v"(g35),[g37]"+&v"(g37), \
  [t0]"=&v"(t0),[t1]"=&v"(t1),[t2]"=&v"(t2),[t3]"=&v"(t3),[t4]"=&v"(t4), \
  [t5]"=&v"(t5),[t6]"=&v"(t6),[t7]"=&v"(t7),[t8]"=&v"(t8),[t9]"=&v"(t9)

#define RUN_CHUNK(BODY, XB,X1,X3,X5,X7, YB,Y1,Y3,Y5,Y7) \
  asm volatile(BODY : ST_OUTS \
    : [m1]"v"(m1f),[m3]"v"(m3f),[m5]"v"(m5f),[m7]"v"(m7f),[m8]"v"(m8f), \
      [cB]"v"(XB),[c1]"v"(X1),[c3]"v"(X3),[c5]"v"(X5),[c7]"v"(X7), \
      [nB]"v"(YB),[n1]"v"(Y1),[n3]"v"(Y3),[n5]"v"(Y5),[n7]"v"(Y7) \
    : "vcc","memory")

#define RUN_BDY(BODY) asm volatile(BODY : ST_OUTS :: "vcc","memory")

__launch_bounds__(128, 1)
__global__ void ctc_loss_kernel(const int* __restrict__ y_true,
                                const float* __restrict__ y_pred,
                                float* __restrict__ out) {
    const int b = blockIdx.x;
    const int tid = threadIdx.x;
    const int w = __builtin_amdgcn_readfirstlane(tid >> 6);  // 0=fwd, 1=bwd
    const int l = tid & 63;

    __shared__ float ring[2][4][CH_ * C_];  // 2 waves x 4 bufs x 16x128 = 64 KB

    const int* __restrict__ lab = y_true + b * L_;
    const int4 lv = *(const int4*)(lab + 4 * l);   // labels 4l..4l+3
    const int e1 = lv.x, e3 = lv.y, e5 = lv.z, e7 = lv.w;
    const int em1 = (l > 0) ? lab[4 * l - 1] : -1;
    const float m1f = ((l > 0) && (e1 != em1)) ? 1.0f : 0.0f;  // skip gates
    const float m3f = (e3 != e1) ? 1.0f : 0.0f;
    const float m5f = (e5 != e3) ? 1.0f : 0.0f;
    const float m7f = (e7 != e5) ? 1.0f : 0.0f;
    const float m8f = (l == 63) ? 1.0f : 0.0f;     // state-512 coupling gate

    const float* __restrict__ base = y_pred + (size_t)b * (T_ * C_);

    // per-buf column base pointers (LDS addrspace(3): 32-bit vaddrs)
    lds_f* lb = (lds_f*)&ring[0][0][0];
    lds_f* q0 = lb + w * 8192;
    lds_f* q1 = q0 + 2048;
    lds_f* q2 = q0 + 4096;
    lds_f* q3 = q0 + 6144;
    lds_f *cB0 = q0 + BLANK_, *c10 = q0 + e1, *c30 = q0 + e3,
          *c50 = q0 + e5, *c70 = q0 + e7;
    lds_f *cB1 = q1 + BLANK_, *c11 = q1 + e1, *c31 = q1 + e3,
          *c51 = q1 + e5, *c71 = q1 + e7;
    lds_f *cB2 = q2 + BLANK_, *c12 = q2 + e1, *c32 = q2 + e3,
          *c52 = q2 + e5, *c72 = q2 + e7;
    lds_f *cB3 = q3 + BLANK_, *c13 = q3 + e1, *c33 = q3 + e3,
          *c53 = q3 + e5, *c73 = q3 + e7;

    auto issueF = [&](int c, int buf) {
        const float* g = base + (size_t)c * CH_ * C_ + 4 * l;
#pragma unroll
        for (int i = 0; i < 8; ++i)
            gl2lds16(g + i * 256, &ring[0][buf][i * 256]);
    };
    auto issueB = [&](int qc, int buf) {  // qc 0 -> global chunk 127
        const float* g = base + (size_t)(127 - qc) * CH_ * C_ + 4 * l;
#pragma unroll
        for (int i = 0; i < 8; ++i)
            gl2lds16(g + i * 256, &ring[1][buf][i * 256]);
    };

    // recurrence state + lookahead slots + asm scratch (all live variables)
    float a0 = 0.f, a1 = 0.f, a2 = 0.f, a3 = 0.f, a4 = 0.f,
          a5 = 0.f, a6 = 0.f, a7 = 0.f, a8 = 0.f;
    int E = SENT_;
    float ups = 1.0f;
    float g0b = 0.f, g01 = 0.f, g03 = 0.f, g05 = 0.f, g07 = 0.f,
          g1b = 0.f, g11 = 0.f, g13 = 0.f, g15 = 0.f, g17 = 0.f,
          g2b = 0.f, g21 = 0.f, g23 = 0.f, g25 = 0.f, g27 = 0.f,
          g3b = 0.f, g31 = 0.f, g33 = 0.f, g35 = 0.f, g37 = 0.f;
    float t0, t1, t2, t3, t4, t5, t6, t7, t8, t9;

    if (w == 0) {
        // ======== forward: chunks 0..63 (t = 0..1023) ========
        issueF(0, 0); issueF(1, 1); issueF(2, 2);
        WAIT_VM(8);                        // chunks 0,1 landed; 2 in flight
        issueF(3, 3);
        {
            const float* rbf = &ring[0][0][0];
            const float i0 = rbf[BLANK_] + EPSF;
            const float i1 = rbf[e1] + EPSF;
            if (l == 0) { a0 = i0; a1 = i1; E = 0; }
        }
        RUN_BDY(BDYF);                     // seeds lane1's adoption of E
        DRAIN_LGKM();
        RUN_CHUNK(FWD_FIRST_BODY, cB0,c10,c30,c50,c70, cB1,c11,c31,c51,c71);
        WAIT_VM(8); issueF(4, 0);
        RUN_CHUNK(FWD_FULL_BODY, cB1,c11,c31,c51,c71, cB2,c12,c32,c52,c72);
        WAIT_VM(8); issueF(5, 1);
        RUN_CHUNK(FWD_FULL_BODY, cB2,c12,c32,c52,c72, cB3,c13,c33,c53,c73);
        WAIT_VM(8); issueF(6, 2);
        RUN_CHUNK(FWD_FULL_BODY, cB3,c13,c33,c53,c73, cB0,c10,c30,c50,c70);
#pragma unroll 1
        for (int m = 1; m <= 14; ++m) {    // chunks 4..59
            WAIT_VM(8); issueF(4 * m + 3, 3);
            RUN_CHUNK(FWD_FULL_BODY, cB0,c10,c30,c50,c70, cB1,c11,c31,c51,c71);
            WAIT_VM(8); issueF(4 * m + 4, 0);
            RUN_CHUNK(FWD_FULL_BODY, cB1,c11,c31,c51,c71, cB2,c12,c32,c52,c72);
            WAIT_VM(8); issueF(4 * m + 5, 1);
            RUN_CHUNK(FWD_FULL_BODY, cB2,c12,c32,c52,c72, cB3,c13,c33,c53,c73);
            WAIT_VM(8); issueF(4 * m + 6, 2);
            RUN_CHUNK(FWD_FULL_BODY, cB3,c13,c33,c53,c73, cB0,c10,c30,c50,c70);
        }
        WAIT_VM(8); issueF(63, 3);         // chunk 60
        RUN_CHUNK(FWD_FULL_BODY, cB0,c10,c30,c50,c70, cB1,c11,c31,c51,c71);
        WAIT_VM(8);                        // chunk 61
        RUN_CHUNK(FWD_FULL_BODY, cB1,c11,c31,c51,c71, cB2,c12,c32,c52,c72);
        WAIT_VM(0);                        // chunk 62
        RUN_CHUNK(FWD_FULL_BODY, cB2,c12,c32,c52,c72, cB3,c13,c33,c53,c73);
        RUN_CHUNK(FWD_LAST_BODY, cB3,c13,c33,c53,c73, cB3,c13,c33,c53,c73);
        // a0..a8, E now hold alpha_{1023}
    } else {
        // ======== backward: t = 2047..1024 (qc = 0..63) ========
        issueB(0, 0); issueB(1, 1); issueB(2, 2);
        WAIT_VM(8);
        issueB(3, 3);
        if (l == 63) { a7 = 1.0f; a8 = 1.0f; E = 0; }  // c_2048 = f
        RUN_BDY(BDYB);                     // seeds lane62's adoption of E
        DRAIN_LGKM();
        RUN_CHUNK(BWD_FIRST_BODY, cB0,c10,c30,c50,c70, cB1,c11,c31,c51,c71);
        WAIT_VM(8); issueB(4, 0);
        RUN_CHUNK(BWD_FULL_BODY, cB1,c11,c31,c51,c71, cB2,c12,c32,c52,c72);
        WAIT_VM(8); issueB(5, 1);
        RUN_CHUNK(BWD_FULL_BODY, cB2,c12,c32,c52,c72, cB3,c13,c33,c53,c73);
        WAIT_VM(8); issueB(6, 2);
        RUN_CHUNK(BWD_FULL_BODY, cB3,c13,c33,c53,c73, cB0,c10,c30,c50,c70);
#pragma unroll 1
        for (int m = 1; m <= 14; ++m) {
            WAIT_VM(8); issueB(4 * m + 3, 3);
            RUN_CHUNK(BWD_FULL_BODY, cB0,c10,c30,c50,c70, cB1,c11,c31,c51,c71);
            WAIT_VM(8); issueB(4 * m + 4, 0);
            RUN_CHUNK(BWD_FULL_BODY, cB1,c11,c31,c51,c71, cB2,c12,c32,c52,c72);
            WAIT_VM(8); issueB(4 * m + 5, 1);
            RUN_CHUNK(BWD_FULL_BODY, cB2,c12,c32,c52,c72, cB3,c13,c33,c53,c73);
            WAIT_VM(8); issueB(4 * m + 6, 2);
            RUN_CHUNK(BWD_FULL_BODY, cB3,c13,c33,c53,c73, cB0,c10,c30,c50,c70);
        }
        WAIT_VM(8); issueB(63, 3);
        RUN_CHUNK(BWD_FULL_BODY, cB0,c10,c30,c50,c70, cB1,c11,c31,c51,c71);
        WAIT_VM(8);
        RUN_CHUNK(BWD_FULL_BODY, cB1,c11,c31,c51,c71, cB2,c12,c32,c52,c72);
        WAIT_VM(0);
        RUN_CHUNK(BWD_FULL_BODY, cB2,c12,c32,c52,c72, cB3,c13,c33,c53,c73);
        RUN_CHUNK(BWD_LAST_BODY, cB3,c13,c33,c53,c73, cB3,c13,c33,c53,c73);
        // a0..a8, E now hold c_{1024}; export via own ring (drained)
        float* xf = &ring[1][0][0];
        xf[0 * 64 + l] = a0; xf[1 * 64 + l] = a1; xf[2 * 64 + l] = a2;
        xf[3 * 64 + l] = a3; xf[4 * 64 + l] = a4; xf[5 * 64 + l] = a5;
        xf[6 * 64 + l] = a6; xf[7 * 64 + l] = a7; xf[8 * 64 + l] = a8;
        ((int*)xf)[9 * 64 + l] = E;
    }

    __syncthreads();

    if (w == 0) {
        // p = <alpha_{1023}, c_{1024}>: lane dot then 64-lane logsumexp.
        const float* xf = &ring[1][0][0];
        float sd = a0 * xf[0 * 64 + l];
        sd = fmaf(a1, xf[1 * 64 + l], sd);
        sd = fmaf(a2, xf[2 * 64 + l], sd);
        sd = fmaf(a3, xf[3 * 64 + l], sd);
        sd = fmaf(a4, xf[4 * 64 + l], sd);
        sd = fmaf(a5, xf[5 * 64 + l], sd);
        sd = fmaf(a6, xf[6 * 64 + l], sd);
        sd = fmaf(a7, xf[7 * 64 + l], sd);
        sd = fmaf(a8, xf[8 * 64 + l], sd);
        const int E2 = ((const int*)xf)[9 * 64 + l];
        const bool nz = (sd > 0.0f);
        int Es = nz ? (E + E2) : SENT_;
        int M = Es;
#pragma unroll
        for (int o = 32; o; o >>= 1) M = max(M, __shfl_xor(M, o));
        int d = Es - M;
        d = max(d, -126);
        float val = nz ? sd * __uint_as_float((unsigned)(d + 127) << 23) : 0.0f;
#pragma unroll
        for (int o = 32; o; o >>= 1) val += __shfl_xor(val, o);
        if (l == 0) out[b] = -(__logf(val) + (float)M * LN2F);
    }
}

extern "C" void kernel_launch(void* const* d_in, const int* in_sizes, int n_in,
                              void* d_out, int out_size, void* d_ws, size_t ws_size,
                              hipStream_t stream) {
    const int* y_true = (const int*)d_in[0];
    const float* y_pred = (const float*)d_in[1];
    float* out = (float*)d_out;
    ctc_loss_kernel<<<B_, 128, 0, stream>>>(y_true, y_pred, out);
}

// Round 8
// 171.770 us; speedup vs baseline: 1.5716x; 1.0747x over previous
//
#include <hip/hip_runtime.h>

// CTC batch cost (Keras ctc_batch_cost, full lengths).
// B=64, T=2048, C=128 (blank=127), L=256, S=513.
//
// Round-20: ISSUE-SLOT DIET v2 (on the R19 asm framework).
// Model (fits R12-R19): lone-wave issue-slot-bound; per-step ~47 slots
// (38 VALU + 5 DS + waits); duration ~ slot count (R17 2x slots = 2x time;
// R13 vs R19 VALU-cycles identical -> compiler was already tight). Cuts:
//  (1) STEPB rewritten fully in-place: 34 -> 29 VALU (drop 3 movs + 1 mov
//      via v_fma; pure reordering of independent ops).
//  (2) z0 zero-register DPP: wave_shr:1 never writes lane0 (wave_shl:1
//      never writes lane63), so a dedicated always-zero dest register
//      removes the per-step "v_mov 0" (-1/step).
//  (3) Fast boundary for post-frontier chunks (>=28; frontier completes
//      by t~260+-2sigma, switch at t=448 is >60 sigma safe): no sentinel,
//      v_max3 tree (8->4), and the renorm scale FOLDED into the next
//      step's eps-load: fma(g, sc, eps*sc). Bit-identical: sc=2^k commutes
//      with rounding; cross-lane term uses pre-update ups for fwd (exact
//      derivation: needed factor = 2^(Enbr_old - Eself_old)) and new ups
//      for bwd (sender's fold already normalizes its export). Boundary
//      34 -> 16. Final quad of each chain uses a FULL boundary so the
//      (mantissa, E) pair is consistent for the combine dot.
//  (4) lgkm wait merged to one lgkmcnt(10) per 2 steps (in-order retire
//      covers both groups)  -0.5/step.
// Unchanged: fwd/bwd split waves, 4-buf LDS rings, gl2lds16 DMA,
// WAIT_VM(8) never-drain, meet at t=1023/1024, 9-FMA dot + logsumexp.

#define B_ 64
#define T_ 2048
#define C_ 128
#define L_ 256
#define BLANK_ (C_ - 1)
#define EPSF 1e-7f
#define LN2F 0.69314718055994530942f
#define CH_ 16
#define SENT_ (-(1 << 28))    // "lane is all-zero" exponent sentinel

typedef __attribute__((address_space(1))) const void glob_cv;
typedef __attribute__((address_space(3))) void lds_v;
typedef __attribute__((address_space(3))) float lds_f;

__device__ __forceinline__ void gl2lds16(const void* g, void* l) {
    __builtin_amdgcn_global_load_lds((glob_cv*)g, (lds_v*)l, 16, 0, 0);
}

#define WAIT_VM(n) asm volatile("s_waitcnt vmcnt(" #n ")" ::: "memory")
#define DRAIN_LGKM() asm volatile("s_waitcnt lgkmcnt(0)" ::: "memory")

#define XS_(x) #x
#define XS(x) XS_(x)

#define WLG(n) "s_waitcnt lgkmcnt(" #n ")\n\t"
#define NW ""

// 5 gathers of one row into lookahead slot S (current buf / next buf).
#define FILLC(S, OFF) \
  "ds_read_b32 %[g" #S "b], %[cB] offset:" XS(OFF) "\n\t" \
  "ds_read_b32 %[g" #S "1], %[c1] offset:" XS(OFF) "\n\t" \
  "ds_read_b32 %[g" #S "3], %[c3] offset:" XS(OFF) "\n\t" \
  "ds_read_b32 %[g" #S "5], %[c5] offset:" XS(OFF) "\n\t" \
  "ds_read_b32 %[g" #S "7], %[c7] offset:" XS(OFF) "\n\t"
#define FILLN(S, OFF) \
  "ds_read_b32 %[g" #S "b], %[nB] offset:" XS(OFF) "\n\t" \
  "ds_read_b32 %[g" #S "1], %[n1] offset:" XS(OFF) "\n\t" \
  "ds_read_b32 %[g" #S "3], %[n3] offset:" XS(OFF) "\n\t" \
  "ds_read_b32 %[g" #S "5], %[n5] offset:" XS(OFF) "\n\t" \
  "ds_read_b32 %[g" #S "7], %[n7] offset:" XS(OFF) "\n\t"

// shared forward-step core (24 instrs incl DPP pair). eps pre-applied in t1-t5.
#define FCORE \
  "v_mov_b32_dpp %[z0], %[va7] wave_shr:1 row_mask:0xf bank_mask:0xf\n\t" \
  "v_mul_f32 %[t0], %[z0], %[ups]\n\t" \
  "v_add_f32 %[t6], %[va0], %[va1]\n\t" \
  "v_fmac_f32 %[t6], %[m1], %[t0]\n\t" \
  "v_add_f32 %[va0], %[va0], %[t0]\n\t" \
  "v_mul_f32 %[va0], %[va0], %[t1]\n\t" \
  "v_add_f32 %[t7], %[va1], %[va2]\n\t" \
  "v_add_f32 %[t8], %[va2], %[va3]\n\t" \
  "v_fmac_f32 %[t8], %[m3], %[va1]\n\t" \
  "v_mul_f32 %[va1], %[t6], %[t2]\n\t" \
  "v_mul_f32 %[va2], %[t7], %[t1]\n\t" \
  "v_add_f32 %[t6], %[va3], %[va4]\n\t" \
  "v_add_f32 %[t7], %[va4], %[va5]\n\t" \
  "v_fmac_f32 %[t7], %[m5], %[va3]\n\t" \
  "v_mul_f32 %[va3], %[t8], %[t3]\n\t" \
  "v_mul_f32 %[va4], %[t6], %[t1]\n\t" \
  "v_add_f32 %[t6], %[va5], %[va6]\n\t" \
  "v_add_f32 %[t8], %[va6], %[va7]\n\t" \
  "v_fmac_f32 %[t8], %[m7], %[va5]\n\t" \
  "v_mul_f32 %[va5], %[t7], %[t4]\n\t" \
  "v_mul_f32 %[va6], %[t6], %[t1]\n\t" \
  "v_fmac_f32 %[va8], %[m8], %[va7]\n\t" \
  "v_mul_f32 %[va7], %[t8], %[t5]\n\t" \
  "v_mul_f32 %[va8], %[va8], %[t1]\n\t"

// plain fwd step: literal-eps adds. eps bits 0x33d6bf95.
#define STEPF(S, W, FILLS) W \
  "v_add_f32 %[t1], 0x33d6bf95, %[g" #S "b]\n\t" \
  "v_add_f32 %[t2], 0x33d6bf95, %[g" #S "1]\n\t" \
  "v_add_f32 %[t3], 0x33d6bf95, %[g" #S "3]\n\t" \
  "v_add_f32 %[t4], 0x33d6bf95, %[g" #S "5]\n\t" \
  "v_add_f32 %[t5], 0x33d6bf95, %[g" #S "7]\n\t" \
  FCORE FILLS

// post-boundary fwd step: folded-scale eps (fma), OLD ups, then adopt upn.
#define STEPF1(S, W, FILLS) W \
  "v_fma_f32 %[t1], %[g" #S "b], %[sc], %[esc]\n\t" \
  "v_fma_f32 %[t2], %[g" #S "1], %[sc], %[esc]\n\t" \
  "v_fma_f32 %[t3], %[g" #S "3], %[sc], %[esc]\n\t" \
  "v_fma_f32 %[t4], %[g" #S "5], %[sc], %[esc]\n\t" \
  "v_fma_f32 %[t5], %[g" #S "7], %[sc], %[esc]\n\t" \
  FCORE \
  "v_mov_b32 %[ups], %[upn]\n\t" \
  FILLS

// shared backward-step core (24 instrs), fully in-place. UPSREG selects
// %[ups] (plain) or %[upn] (post-boundary).
#define BCORE(UPSREG) \
  "v_mul_f32 %[va0], %[va0], %[t1]\n\t" \
  "v_mul_f32 %[va1], %[va1], %[t2]\n\t" \
  "v_fma_f32 %[t6], %[m1], %[va1], %[va0]\n\t" \
  "v_mul_f32 %[va2], %[va2], %[t1]\n\t" \
  "v_mul_f32 %[va3], %[va3], %[t3]\n\t" \
  "v_mul_f32 %[va4], %[va4], %[t1]\n\t" \
  "v_mul_f32 %[va5], %[va5], %[t4]\n\t" \
  "v_mul_f32 %[va6], %[va6], %[t1]\n\t" \
  "v_mul_f32 %[va7], %[va7], %[t5]\n\t" \
  "v_mul_f32 %[va8], %[va8], %[t1]\n\t" \
  "v_mov_b32_dpp %[z0], %[t6] wave_shl:1 row_mask:0xf bank_mask:0xf\n\t" \
  "v_mul_f32 %[t0], %[z0], " UPSREG "\n\t" \
  "v_add_f32 %[va0], %[va0], %[va1]\n\t" \
  "v_add_f32 %[va1], %[va1], %[va2]\n\t" \
  "v_fmac_f32 %[va1], %[m3], %[va3]\n\t" \
  "v_add_f32 %[va2], %[va2], %[va3]\n\t" \
  "v_add_f32 %[va3], %[va3], %[va4]\n\t" \
  "v_fmac_f32 %[va3], %[m5], %[va5]\n\t" \
  "v_add_f32 %[va4], %[va4], %[va5]\n\t" \
  "v_add_f32 %[va5], %[va5], %[va6]\n\t" \
  "v_fmac_f32 %[va5], %[m7], %[va7]\n\t" \
  "v_add_f32 %[va6], %[va6], %[va7]\n\t" \
  "v_add_f32 %[va7], %[va7], %[t0]\n\t" \
  "v_fmac_f32 %[va7], %[m8], %[va8]\n\t"

#define STEPB(S, W, FILLS) W \
  "v_add_f32 %[t1], 0x33d6bf95, %[g" #S "b]\n\t" \
  "v_add_f32 %[t2], 0x33d6bf95, %[g" #S "1]\n\t" \
  "v_add_f32 %[t3], 0x33d6bf95, %[g" #S "3]\n\t" \
  "v_add_f32 %[t4], 0x33d6bf95, %[g" #S "5]\n\t" \
  "v_add_f32 %[t5], 0x33d6bf95, %[g" #S "7]\n\t" \
  BCORE("%[ups]") FILLS

#define STEPB1(S, W, FILLS) W \
  "v_fma_f32 %[t1], %[g" #S "b], %[sc], %[esc]\n\t" \
  "v_fma_f32 %[t2], %[g" #S "1], %[sc], %[esc]\n\t" \
  "v_fma_f32 %[t3], %[g" #S "3], %[sc], %[esc]\n\t" \
  "v_fma_f32 %[t4], %[g" #S "5], %[sc], %[esc]\n\t" \
  "v_fma_f32 %[t5], %[g" #S "7], %[sc], %[esc]\n\t" \
  BCORE("%[upn]") \
  "v_mov_b32 %[ups], %[upn]\n\t" \
  FILLS

// FULL boundary (frontier-safe, rescales in place) + fold-state reset.
#define BDY_HEAD \
  "v_max_f32 %[t1], %[va0], %[va1]\n\t" \
  "v_max_f32 %[t2], %[va2], %[va3]\n\t" \
  "v_max_f32 %[t3], %[va4], %[va5]\n\t" \
  "v_max_f32 %[t4], %[va6], %[va7]\n\t" \
  "v_max_f32 %[t1], %[t1], %[t2]\n\t" \
  "v_max_f32 %[t3], %[t3], %[t4]\n\t" \
  "v_max_f32 %[t1], %[t1], %[t3]\n\t" \
  "v_max_f32 %[t1], %[t1], %[va8]\n\t" \
  "v_cmp_ne_u32 vcc, 0, %[t1]\n\t" \
  "v_lshrrev_b32 %[t2], 23, %[t1]\n\t" \
  "v_sub_u32 %[t3], 0xfe, %[t2]\n\t" \
  "v_lshlrev_b32 %[t3], 23, %[t3]\n\t" \
  "v_cndmask_b32 %[t3], 1.0, %[t3], vcc\n\t" \
  "v_mul_f32 %[va0], %[va0], %[t3]\n\t" \
  "v_mul_f32 %[va1], %[va1], %[t3]\n\t" \
  "v_mul_f32 %[va2], %[va2], %[t3]\n\t" \
  "v_mul_f32 %[va3], %[va3], %[t3]\n\t" \
  "v_mul_f32 %[va4], %[va4], %[t3]\n\t" \
  "v_mul_f32 %[va5], %[va5], %[t3]\n\t" \
  "v_mul_f32 %[va6], %[va6], %[t3]\n\t" \
  "v_mul_f32 %[va7], %[va7], %[t3]\n\t" \
  "v_mul_f32 %[va8], %[va8], %[t3]\n\t" \
  "v_add_u32 %[t2], 0xffffff81, %[t2]\n\t" \
  "v_add_u32 %[t2], %[E], %[t2]\n\t" \
  "v_mov_b32 %[t4], 0xf0000000\n\t" \
  "v_cndmask_b32 %[E], %[t4], %[t2], vcc\n\t" \
  "v_mov_b32 %[t5], 0xf0000000\n\t" \
  "s_nop 1\n\t"
#define BDY_TAIL \
  "v_cmp_ne_u32 vcc, 0xf0000000, %[E]\n\t" \
  "v_cndmask_b32 %[E], %[t5], %[E], vcc\n\t" \
  "v_sub_u32 %[t6], %[t5], %[E]\n\t" \
  "v_max_i32 %[t6], 0xffffff82, %[t6]\n\t" \
  "v_min_i32 %[t6], 0x78, %[t6]\n\t" \
  "v_add_u32 %[t6], 0x7f, %[t6]\n\t" \
  "v_lshlrev_b32 %[ups], 23, %[t6]\n\t" \
  "v_mov_b32 %[sc], 1.0\n\t" \
  "v_mov_b32 %[esc], 0x33d6bf95\n\t" \
  "v_mov_b32 %[upn], %[ups]\n\t"
#define BDYF_FULL BDY_HEAD \
  "v_mov_b32_dpp %[t5], %[E] wave_shr:1 row_mask:0xf bank_mask:0xf\n\t" \
  BDY_TAIL
#define BDYB_FULL BDY_HEAD \
  "v_mov_b32_dpp %[t5], %[E] wave_shl:1 row_mask:0xf bank_mask:0xf\n\t" \
  BDY_TAIL

// FAST boundary (post-frontier): no sentinel, scale folded into next step.
#define FBDY_HEAD \
  "v_max3_f32 %[t1], %[va0], %[va1], %[va2]\n\t" \
  "v_max3_f32 %[t2], %[va3], %[va4], %[va5]\n\t" \
  "v_max3_f32 %[t3], %[va6], %[va7], %[va8]\n\t" \
  "v_max3_f32 %[t1], %[t1], %[t2], %[t3]\n\t" \
  "v_lshrrev_b32 %[t2], 23, %[t1]\n\t" \
  "v_add_u32 %[t4], 0xffffff81, %[t2]\n\t" \
  "v_add_u32 %[E], %[E], %[t4]\n\t" \
  "v_sub_u32 %[t3], 0xfe, %[t2]\n\t" \
  "v_lshlrev_b32 %[sc], 23, %[t3]\n\t" \
  "v_mul_f32 %[esc], 0x33d6bf95, %[sc]\n\t"
#define FBDY_TAIL \
  "v_sub_u32 %[t4], %[t5], %[E]\n\t" \
  "v_max_i32 %[t4], 0xffffff82, %[t4]\n\t" \
  "v_min_i32 %[t4], 0x78, %[t4]\n\t" \
  "v_add_u32 %[t4], 0x7f, %[t4]\n\t" \
  "v_lshlrev_b32 %[upn], 23, %[t4]\n\t"
#define BDYF_FAST FBDY_HEAD \
  "v_mov_b32_dpp %[t5], %[E] wave_shr:1 row_mask:0xf bank_mask:0xf\n\t" \
  FBDY_TAIL
#define BDYB_FAST FBDY_HEAD \
  "v_mov_b32_dpp %[t5], %[E] wave_shl:1 row_mask:0xf bank_mask:0xf\n\t" \
  FBDY_TAIL

// ---- forward chunk bodies (fills: row*512 within buf) ----
#define FQ1(BDY) STEPF1(0,WLG(10),FILLC(0,2048)) STEPF(1,NW,FILLC(1,2560)) \
                 STEPF(2,WLG(10),FILLC(2,3072)) STEPF(3,NW,FILLC(3,3584)) BDY
#define FQ2(BDY) STEPF1(0,WLG(10),FILLC(0,4096)) STEPF(1,NW,FILLC(1,4608)) \
                 STEPF(2,WLG(10),FILLC(2,5120)) STEPF(3,NW,FILLC(3,5632)) BDY
#define FQ3(BDY) STEPF1(0,WLG(10),FILLC(0,6144)) STEPF(1,NW,FILLC(1,6656)) \
                 STEPF(2,WLG(10),FILLC(2,7168)) STEPF(3,NW,FILLC(3,7680)) BDY
#define FQ4(BDY) STEPF1(0,WLG(10),FILLN(0,0))    STEPF(1,NW,FILLN(1,512)) \
                 STEPF(2,WLG(10),FILLN(2,1024)) STEPF(3,NW,FILLN(3,1536)) BDY

#define FWD_FULL_BODY FQ1(BDYF_FULL) FQ2(BDYF_FULL) FQ3(BDYF_FULL) FQ4(BDYF_FULL)
#define FWD_FAST_BODY FQ1(BDYF_FAST) FQ2(BDYF_FAST) FQ3(BDYF_FAST) FQ4(BDYF_FAST)
#define FWD_FIRST_BODY \
  FILLC(1,512) FILLC(2,1024) FILLC(3,1536) FILLC(0,2048) \
  STEPF1(1,WLG(10),FILLC(1,2560)) STEPF(2,NW,FILLC(2,3072)) \
  STEPF(3,WLG(10),FILLC(3,3584)) BDYF_FULL \
  FQ2(BDYF_FULL) FQ3(BDYF_FULL) FQ4(BDYF_FULL)
#define FWD_LAST_BODY FQ1(BDYF_FAST) FQ2(BDYF_FAST) FQ3(BDYF_FAST) \
  STEPF1(0,WLG(10),"") STEPF(1,NW,"") STEPF(2,WLG(5),"") STEPF(3,WLG(0),"") \
  BDYF_FULL

// ---- backward chunk bodies ----
#define BQ1(BDY) STEPB1(0,WLG(10),FILLC(0,5632)) STEPB(1,NW,FILLC(1,5120)) \
                 STEPB(2,WLG(10),FILLC(2,4608)) STEPB(3,NW,FILLC(3,4096)) BDY
#define BQ2(BDY) STEPB1(0,WLG(10),FILLC(0,3584)) STEPB(1,NW,FILLC(1,3072)) \
                 STEPB(2,WLG(10),FILLC(2,2560)) STEPB(3,NW,FILLC(3,2048)) BDY
#define BQ3(BDY) STEPB1(0,WLG(10),FILLC(0,1536)) STEPB(1,NW,FILLC(1,1024)) \
                 STEPB(2,WLG(10),FILLC(2,512))  STEPB(3,NW,FILLC(3,0))    BDY
#define BQ4(BDY) STEPB1(0,WLG(10),FILLN(0,7680)) STEPB(1,NW,FILLN(1,7168)) \
                 STEPB(2,WLG(10),FILLN(2,6656)) STEPB(3,NW,FILLN(3,6144)) BDY

#define BWD_FULL_BODY BQ1(BDYB_FULL) BQ2(BDYB_FULL) BQ3(BDYB_FULL) BQ4(BDYB_FULL)
#define BWD_FAST_BODY BQ1(BDYB_FAST) BQ2(BDYB_FAST) BQ3(BDYB_FAST) BQ4(BDYB_FAST)
#define BWD_FIRST_BODY \
  FILLC(0,7680) FILLC(1,7168) FILLC(2,6656) FILLC(3,6144) \
  BWD_FULL_BODY
#define BWD_LAST_BODY BQ1(BDYB_FAST) BQ2(BDYB_FAST) BQ3(BDYB_FAST) \
  STEPB1(0,WLG(10),"") STEPB(1,NW,"") STEPB(2,WLG(5),"") STEPB(3,WLG(0),"") \
  BDYB_FULL

// All outputs early-clobber.
#define ST_OUTS \
  [va0]"+&v"(a0),[va1]"+&v"(a1),[va2]"+&v"(a2),[va3]"+&v"(a3), \
  [va4]"+&v"(a4),[va5]"+&v"(a5),[va6]"+&v"(a6),[va7]"+&v"(a7), \
  [va8]"+&v"(a8),[E]"+&v"(E),[ups]"+&v"(ups),[upn]"+&v"(upn), \
  [sc]"+&v"(sc),[esc]"+&v"(esc),[z0]"+&v"(z0), \
  [g0b]"+&v"(g0b),[g01]"+&v"(g01),[g03]"+&v"(g03),[g05]"+&v"(g05),[g07]"+&v"(g07), \
  [g1b]"+&v"(g1b),[g11]"+&v"(g11),[g13]"+&v"(g13),[g15]"+&v"(g15),[g17]"+&v"(g17), \
  [g2b]"+&v"(g2b),[g21]"+&v"(g21),[g23]"+&v"(g23),[g25]"+&v"(g25),[g27]"+&v"(g27), \
  [g3b]"+&v"(g3b),[g31]"+&v"(g31),[g33]"+&v"(g33),[g35]"+&v"(g35),[g37]"+&v"(g37), \
  [t0]"=&v"(t0),[t1]"=&v"(t1),[t2]"=&v"(t2),[t3]"=&v"(t3),[t4]"=&v"(t4), \
  [t5]"=&v"(t5),[t6]"=&v"(t6),[t7]"=&v"(t7),[t8]"=&v"(t8)

#define RUN_CHUNK(BODY, XB,X1,X3,X5,X7, YB,Y1,Y3,Y5,Y7) \
  asm volatile(BODY : ST_OUTS \
    : [m1]"v"(m1f),[m3]"v"(m3f),[m5]"v"(m5f),[m7]"v"(m7f),[m8]"v"(m8f), \
      [cB]"v"(XB),[c1]"v"(X1),[c3]"v"(X3),[c5]"v"(X5),[c7]"v"(X7), \
      [nB]"v"(YB),[n1]"v"(Y1),[n3]"v"(Y3),[n5]"v"(Y5),[n7]"v"(Y7) \
    : "vcc","memory")

#define RUN_BDY(BODY) asm volatile(BODY : ST_OUTS :: "vcc","memory")

__launch_bounds__(128, 1)
__global__ void ctc_loss_kernel(const int* __restrict__ y_true,
                                const float* __restrict__ y_pred,
                                float* __restrict__ out) {
    const int b = blockIdx.x;
    const int tid = threadIdx.x;
    const int w = __builtin_amdgcn_readfirstlane(tid >> 6);  // 0=fwd, 1=bwd
    const int l = tid & 63;

    __shared__ float ring[2][4][CH_ * C_];  // 2 waves x 4 bufs x 16x128 = 64 KB

    const int* __restrict__ lab = y_true + b * L_;
    const int4 lv = *(const int4*)(lab + 4 * l);   // labels 4l..4l+3
    const int e1 = lv.x, e3 = lv.y, e5 = lv.z, e7 = lv.w;
    const int em1 = (l > 0) ? lab[4 * l - 1] : -1;
    const float m1f = ((l > 0) && (e1 != em1)) ? 1.0f : 0.0f;  // skip gates
    const float m3f = (e3 != e1) ? 1.0f : 0.0f;
    const float m5f = (e5 != e3) ? 1.0f : 0.0f;
    const float m7f = (e7 != e5) ? 1.0f : 0.0f;
    const float m8f = (l == 63) ? 1.0f : 0.0f;     // state-512 coupling gate

    const float* __restrict__ base = y_pred + (size_t)b * (T_ * C_);

    // per-buf column base pointers (LDS addrspace(3): 32-bit vaddrs)
    lds_f* lb = (lds_f*)&ring[0][0][0];
    lds_f* q0 = lb + w * 8192;
    lds_f* q1 = q0 + 2048;
    lds_f* q2 = q0 + 4096;
    lds_f* q3 = q0 + 6144;
    lds_f *cB0 = q0 + BLANK_, *c10 = q0 + e1, *c30 = q0 + e3,
          *c50 = q0 + e5, *c70 = q0 + e7;
    lds_f *cB1 = q1 + BLANK_, *c11 = q1 + e1, *c31 = q1 + e3,
          *c51 = q1 + e5, *c71 = q1 + e7;
    lds_f *cB2 = q2 + BLANK_, *c12 = q2 + e1, *c32 = q2 + e3,
          *c52 = q2 + e5, *c72 = q2 + e7;
    lds_f *cB3 = q3 + BLANK_, *c13 = q3 + e1, *c33 = q3 + e3,
          *c53 = q3 + e5, *c73 = q3 + e7;

    auto issueF = [&](int c, int buf) {
        const float* g = base + (size_t)c * CH_ * C_ + 4 * l;
#pragma unroll
        for (int i = 0; i < 8; ++i)
            gl2lds16(g + i * 256, &ring[0][buf][i * 256]);
    };
    auto issueB = [&](int qc, int buf) {  // qc 0 -> global chunk 127
        const float* g = base + (size_t)(127 - qc) * CH_ * C_ + 4 * l;
#pragma unroll
        for (int i = 0; i < 8; ++i)
            gl2lds16(g + i * 256, &ring[1][buf][i * 256]);
    };

    // recurrence state + fold state + lookahead + scratch (live variables)
    float a0 = 0.f, a1 = 0.f, a2 = 0.f, a3 = 0.f, a4 = 0.f,
          a5 = 0.f, a6 = 0.f, a7 = 0.f, a8 = 0.f;
    int E = SENT_;
    float ups = 1.0f, upn = 1.0f, sc = 1.0f, esc = EPSF, z0 = 0.0f;
    float g0b = 0.f, g01 = 0.f, g03 = 0.f, g05 = 0.f, g07 = 0.f,
          g1b = 0.f, g11 = 0.f, g13 = 0.f, g15 = 0.f, g17 = 0.f,
          g2b = 0.f, g21 = 0.f, g23 = 0.f, g25 = 0.f, g27 = 0.f,
          g3b = 0.f, g31 = 0.f, g33 = 0.f, g35 = 0.f, g37 = 0.f;
    float t0, t1, t2, t3, t4, t5, t6, t7, t8;

    if (w == 0) {
        // ======== forward: chunks 0..63 (t = 0..1023) ========
        issueF(0, 0); issueF(1, 1); issueF(2, 2);
        WAIT_VM(8);                        // chunks 0,1 landed; 2 in flight
        issueF(3, 3);
        {
            const float* rbf = &ring[0][0][0];
            const float i0 = rbf[BLANK_] + EPSF;
            const float i1 = rbf[e1] + EPSF;
            if (l == 0) { a0 = i0; a1 = i1; E = 0; }
        }
        RUN_BDY(BDYF_FULL);                // seeds lane1's adoption of E
        DRAIN_LGKM();
        RUN_CHUNK(FWD_FIRST_BODY, cB0,c10,c30,c50,c70, cB1,c11,c31,c51,c71);
        WAIT_VM(8); issueF(4, 0);
        RUN_CHUNK(FWD_FULL_BODY, cB1,c11,c31,c51,c71, cB2,c12,c32,c52,c72);
        WAIT_VM(8); issueF(5, 1);
        RUN_CHUNK(FWD_FULL_BODY, cB2,c12,c32,c52,c72, cB3,c13,c33,c53,c73);
        WAIT_VM(8); issueF(6, 2);
        RUN_CHUNK(FWD_FULL_BODY, cB3,c13,c33,c53,c73, cB0,c10,c30,c50,c70);
#pragma unroll 1
        for (int m = 1; m <= 6; ++m) {     // chunks 4..27 (frontier region)
            WAIT_VM(8); issueF(4 * m + 3, 3);
            RUN_CHUNK(FWD_FULL_BODY, cB0,c10,c30,c50,c70, cB1,c11,c31,c51,c71);
            WAIT_VM(8); issueF(4 * m + 4, 0);
            RUN_CHUNK(FWD_FULL_BODY, cB1,c11,c31,c51,c71, cB2,c12,c32,c52,c72);
            WAIT_VM(8); issueF(4 * m + 5, 1);
            RUN_CHUNK(FWD_FULL_BODY, cB2,c12,c32,c52,c72, cB3,c13,c33,c53,c73);
            WAIT_VM(8); issueF(4 * m + 6, 2);
            RUN_CHUNK(FWD_FULL_BODY, cB3,c13,c33,c53,c73, cB0,c10,c30,c50,c70);
        }
#pragma unroll 1
        for (int m = 7; m <= 14; ++m) {    // chunks 28..59 (fast region)
            WAIT_VM(8); issueF(4 * m + 3, 3);
            RUN_CHUNK(FWD_FAST_BODY, cB0,c10,c30,c50,c70, cB1,c11,c31,c51,c71);
            WAIT_VM(8); issueF(4 * m + 4, 0);
            RUN_CHUNK(FWD_FAST_BODY, cB1,c11,c31,c51,c71, cB2,c12,c32,c52,c72);
            WAIT_VM(8); issueF(4 * m + 5, 1);
            RUN_CHUNK(FWD_FAST_BODY, cB2,c12,c32,c52,c72, cB3,c13,c33,c53,c73);
            WAIT_VM(8); issueF(4 * m + 6, 2);
            RUN_CHUNK(FWD_FAST_BODY, cB3,c13,c33,c53,c73, cB0,c10,c30,c50,c70);
        }
        WAIT_VM(8); issueF(63, 3);         // chunk 60
        RUN_CHUNK(FWD_FAST_BODY, cB0,c10,c30,c50,c70, cB1,c11,c31,c51,c71);
        WAIT_VM(8);                        // chunk 61
        RUN_CHUNK(FWD_FAST_BODY, cB1,c11,c31,c51,c71, cB2,c12,c32,c52,c72);
        WAIT_VM(0);                        // chunk 62
        RUN_CHUNK(FWD_FAST_BODY, cB2,c12,c32,c52,c72, cB3,c13,c33,c53,c73);
        RUN_CHUNK(FWD_LAST_BODY, cB3,c13,c33,c53,c73, cB3,c13,c33,c53,c73);
        // a0..a8, E now hold alpha_{1023} (final BDY is FULL -> consistent)
    } else {
        // ======== backward: t = 2047..1024 (qc = 0..63) ========
        issueB(0, 0); issueB(1, 1); issueB(2, 2);
        WAIT_VM(8);
        issueB(3, 3);
        if (l == 63) { a7 = 1.0f; a8 = 1.0f; E = 0; }  // c_2048 = f
        RUN_BDY(BDYB_FULL);                // seeds lane62's adoption of E
        DRAIN_LGKM();
        RUN_CHUNK(BWD_FIRST_BODY, cB0,c10,c30,c50,c70, cB1,c11,c31,c51,c71);
        WAIT_VM(8); issueB(4, 0);
        RUN_CHUNK(BWD_FULL_BODY, cB1,c11,c31,c51,c71, cB2,c12,c32,c52,c72);
        WAIT_VM(8); issueB(5, 1);
        RUN_CHUNK(BWD_FULL_BODY, cB2,c12,c32,c52,c72, cB3,c13,c33,c53,c73);
        WAIT_VM(8); issueB(6, 2);
        RUN_CHUNK(BWD_FULL_BODY, cB3,c13,c33,c53,c73, cB0,c10,c30,c50,c70);
#pragma unroll 1
        for (int m = 1; m <= 6; ++m) {
            WAIT_VM(8); issueB(4 * m + 3, 3);
            RUN_CHUNK(BWD_FULL_BODY, cB0,c10,c30,c50,c70, cB1,c11,c31,c51,c71);
            WAIT_VM(8); issueB(4 * m + 4, 0);
            RUN_CHUNK(BWD_FULL_BODY, cB1,c11,c31,c51,c71, cB2,c12,c32,c52,c72);
            WAIT_VM(8); issueB(4 * m + 5, 1);
            RUN_CHUNK(BWD_FULL_BODY, cB2,c12,c32,c52,c72, cB3,c13,c33,c53,c73);
            WAIT_VM(8); issueB(4 * m + 6, 2);
            RUN_CHUNK(BWD_FULL_BODY, cB3,c13,c33,c53,c73, cB0,c10,c30,c50,c70);
        }
#pragma unroll 1
        for (int m = 7; m <= 14; ++m) {
            WAIT_VM(8); issueB(4 * m + 3, 3);
            RUN_CHUNK(BWD_FAST_BODY, cB0,c10,c30,c50,c70, cB1,c11,c31,c51,c71);
            WAIT_VM(8); issueB(4 * m + 4, 0);
            RUN_CHUNK(BWD_FAST_BODY, cB1,c11,c31,c51,c71, cB2,c12,c32,c52,c72);
            WAIT_VM(8); issueB(4 * m + 5, 1);
            RUN_CHUNK(BWD_FAST_BODY, cB2,c12,c32,c52,c72, cB3,c13,c33,c53,c73);
            WAIT_VM(8); issueB(4 * m + 6, 2);
            RUN_CHUNK(BWD_FAST_BODY, cB3,c13,c33,c53,c73, cB0,c10,c30,c50,c70);
        }
        WAIT_VM(8); issueB(63, 3);
        RUN_CHUNK(BWD_FAST_BODY, cB0,c10,c30,c50,c70, cB1,c11,c31,c51,c71);
        WAIT_VM(8);
        RUN_CHUNK(BWD_FAST_BODY, cB1,c11,c31,c51,c71, cB2,c12,c32,c52,c72);
        WAIT_VM(0);
        RUN_CHUNK(BWD_FAST_BODY, cB2,c12,c32,c52,c72, cB3,c13,c33,c53,c73);
        RUN_CHUNK(BWD_LAST_BODY, cB3,c13,c33,c53,c73, cB3,c13,c33,c53,c73);
        // a0..a8, E now hold c_{1024}; export via own ring (drained)
        float* xf = &ring[1][0][0];
        xf[0 * 64 + l] = a0; xf[1 * 64 + l] = a1; xf[2 * 64 + l] = a2;
        xf[3 * 64 + l] = a3; xf[4 * 64 + l] = a4; xf[5 * 64 + l] = a5;
        xf[6 * 64 + l] = a6; xf[7 * 64 + l] = a7; xf[8 * 64 + l] = a8;
        ((int*)xf)[9 * 64 + l] = E;
    }

    __syncthreads();

    if (w == 0) {
        // p = <alpha_{1023}, c_{1024}>: lane dot then 64-lane logsumexp.
        const float* xf = &ring[1][0][0];
        float sd = a0 * xf[0 * 64 + l];
        sd = fmaf(a1, xf[1 * 64 + l], sd);
        sd = fmaf(a2, xf[2 * 64 + l], sd);
        sd = fmaf(a3, xf[3 * 64 + l], sd);
        sd = fmaf(a4, xf[4 * 64 + l], sd);
        sd = fmaf(a5, xf[5 * 64 + l], sd);
        sd = fmaf(a6, xf[6 * 64 + l], sd);
        sd = fmaf(a7, xf[7 * 64 + l], sd);
        sd = fmaf(a8, xf[8 * 64 + l], sd);
        const int E2 = ((const int*)xf)[9 * 64 + l];
        const bool nz = (sd > 0.0f);
        int Es = nz ? (E + E2) : SENT_;
        int M = Es;
#pragma unroll
        for (int o = 32; o; o >>= 1) M = max(M, __shfl_xor(M, o));
        int d = Es - M;
        d = max(d, -126);
        float val = nz ? sd * __uint_as_float((unsigned)(d + 127) << 23) : 0.0f;
#pragma unroll
        for (int o = 32; o; o >>= 1) val += __shfl_xor(val, o);
        if (l == 0) out[b] = -(__logf(val) + (float)M * LN2F);
    }
}

extern "C" void kernel_launch(void* const* d_in, const int* in_sizes, int n_in,
                              void* d_out, int out_size, void* d_ws, size_t ws_size,
                              hipStream_t stream) {
    const int* y_true = (const int*)d_in[0];
    const float* y_pred = (const float*)d_in[1];
    float* out = (float*)d_out;
    ctc_loss_kernel<<<B_, 128, 0, stream>>>(y_true, y_pred, out);
}

// Round 11
// 160.104 us; speedup vs baseline: 1.6861x; 1.0729x over previous
//
#include <hip/hip_runtime.h>

// CTC batch cost (Keras ctc_batch_cost, full lengths).
// B=64, T=2048, C=128 (blank=127), L=256, S=513.
//
// Round-23 == Round-22 resubmission (previous run died on container infra,
// not on the kernel: no compile error, no counters). See R22 header below.
//
// Round-22: PACKED-FP32 STEP, gfx950-legal (R21 minus v_pk_max_f32).
// R21's compile log proved: v_pk_{add,mul,fma}_f32 and "{vN}" physical-reg
// constraints assemble on gfx950; ONLY v_pk_max_f32 does not exist. This
// round: boundary max trees use scalar v_max3_f32 (same op count); the
// blank-column broadcast drops op_sel (semantics hedge) in favor of one
// v_mov duplicating pb+eps into the pair-high reg. BCORE reordered for
// >=3-slot DPP RAW separation. 22 VALU + 5 DS per step (R20: 29+5).
// State pairs: (a0,a2)@v[48:49], (a4,a6)@v[50:51], (a1,a3)@v[52:53],
// (a5,a7)@v[54:55], a8@v46; z0 DPP dest v47; E v30; ups/upn v37/v38;
// eps pair v[40:41]; sc pair v[42:43]; esc pair v[44:45]; slot pb
// v96/98/100/102 (+dup highs 97/99/101/103); slot pairs v[64..79];
// temps v[80..95]. Formula op order bit-identical to R20 -> absmax 0.0.
// Unchanged: chunk schedule, gl2lds16 DMA, WAIT_VM(8) never-drain,
// WLG(10)-every-2-steps ladder, FULL(<=27)/FAST(>=28) boundary regions
// with sc/esc fold, meet at t=1023/1024, 9-FMA dot + logsumexp.

#define B_ 64
#define T_ 2048
#define C_ 128
#define L_ 256
#define BLANK_ (C_ - 1)
#define EPSF 1e-7f
#define LN2F 0.69314718055994530942f
#define CH_ 16
#define SENT_ (-(1 << 28))

typedef __attribute__((address_space(1))) const void glob_cv;
typedef __attribute__((address_space(3))) void lds_v;
typedef __attribute__((address_space(3))) float lds_f;

__device__ __forceinline__ void gl2lds16(const void* g, void* l) {
    __builtin_amdgcn_global_load_lds((glob_cv*)g, (lds_v*)l, 16, 0, 0);
}

#define WAIT_VM(n) asm volatile("s_waitcnt vmcnt(" #n ")" ::: "memory")
#define DRAIN_LGKM() asm volatile("s_waitcnt lgkmcnt(0)" ::: "memory")

#define XS_(x) #x
#define XS(x) XS_(x)
#define WLG(n) "s_waitcnt lgkmcnt(" #n ")\n\t"
#define NW ""

// ---- fills: 5 ds_read into slot regs ----
#define FILLC(PB,P1,P3,P5,P7,OFF) \
  "ds_read_b32 " PB ", %[cB] offset:" XS(OFF) "\n\t" \
  "ds_read_b32 " P1 ", %[c1] offset:" XS(OFF) "\n\t" \
  "ds_read_b32 " P3 ", %[c3] offset:" XS(OFF) "\n\t" \
  "ds_read_b32 " P5 ", %[c5] offset:" XS(OFF) "\n\t" \
  "ds_read_b32 " P7 ", %[c7] offset:" XS(OFF) "\n\t"
#define FILLN(PB,P1,P3,P5,P7,OFF) \
  "ds_read_b32 " PB ", %[nB] offset:" XS(OFF) "\n\t" \
  "ds_read_b32 " P1 ", %[n1] offset:" XS(OFF) "\n\t" \
  "ds_read_b32 " P3 ", %[n3] offset:" XS(OFF) "\n\t" \
  "ds_read_b32 " P5 ", %[n5] offset:" XS(OFF) "\n\t" \
  "ds_read_b32 " P7 ", %[n7] offset:" XS(OFF) "\n\t"

// ---- forward step core (inputs prepped: v[80:81]=(p1,p3)+e, v[82:83]=
// (p5,p7)+e, PB=pb+e, PBP=(pb+e,pb+e)) : 18 ops ----
#define FCORE(PB,PBP) \
  "v_mov_b32_dpp v47, v55 wave_shr:1 row_mask:0xf bank_mask:0xf\n\t" \
  "v_pk_add_f32 v[84:85], v[48:49], v[52:53]\n\t" \
  "v_pk_add_f32 v[86:87], v[50:51], v[54:55]\n\t" \
  "v_mul_f32 v91, v47, v37\n\t" \
  "v_fmac_f32 v84, %[m1], v91\n\t" \
  "v_fmac_f32 v85, %[m3], v52\n\t" \
  "v_fmac_f32 v86, %[m5], v53\n\t" \
  "v_fmac_f32 v87, %[m7], v54\n\t" \
  "v_add_f32 v88, v48, v91\n\t" \
  "v_add_f32 v89, v52, v49\n\t" \
  "v_add_f32 v92, v53, v50\n\t" \
  "v_add_f32 v93, v54, v51\n\t" \
  "v_fma_f32 v94, %[m8], v55, v46\n\t" \
  "v_pk_mul_f32 v[52:53], v[84:85], v[80:81]\n\t" \
  "v_pk_mul_f32 v[54:55], v[86:87], v[82:83]\n\t" \
  "v_pk_mul_f32 v[48:49], v[88:89], " PBP "\n\t" \
  "v_pk_mul_f32 v[50:51], v[92:93], " PBP "\n\t" \
  "v_mul_f32 v46, v94, " PB "\n\t"

// plain fwd step (literal eps): 22 VALU
#define STEPF(PB,PBH,PBP,P13,P57,W,FILLS) W \
  "v_pk_add_f32 v[80:81], " P13 ", v[40:41]\n\t" \
  "v_pk_add_f32 v[82:83], " P57 ", v[40:41]\n\t" \
  "v_add_f32 " PB ", 0x33d6bf95, " PB "\n\t" \
  "v_mov_b32 " PBH ", " PB "\n\t" \
  FCORE(PB,PBP) FILLS
// quad-leading fwd step (sc/esc fold, OLD ups, then adopt upn)
#define STEPFA(PB,PBH,PBP,P13,P57,W,FILLS) W \
  "v_pk_fma_f32 v[80:81], " P13 ", v[42:43], v[44:45]\n\t" \
  "v_pk_fma_f32 v[82:83], " P57 ", v[42:43], v[44:45]\n\t" \
  "v_fma_f32 " PB ", " PB ", v42, v44\n\t" \
  "v_mov_b32 " PBH ", " PB "\n\t" \
  FCORE(PB,PBP) \
  "v_mov_b32 v37, v38\n\t" \
  FILLS

// ---- backward step core: 18 ops, DPP RAW separation >= 3 ----
#define BCORE(PB,PBP,UPS) \
  "v_pk_mul_f32 v[84:85], v[52:53], v[80:81]\n\t" \
  "v_pk_mul_f32 v[86:87], v[54:55], v[82:83]\n\t" \
  "v_pk_mul_f32 v[88:89], v[48:49], " PBP "\n\t" \
  "v_pk_mul_f32 v[92:93], v[50:51], " PBP "\n\t" \
  "v_fma_f32 v90, %[m1], v84, v88\n\t" \
  "v_mul_f32 v46, v46, " PB "\n\t" \
  "v_pk_add_f32 v[48:49], v[88:89], v[84:85]\n\t" \
  "v_pk_add_f32 v[50:51], v[92:93], v[86:87]\n\t" \
  "v_mov_b32_dpp v47, v90 wave_shl:1 row_mask:0xf bank_mask:0xf\n\t" \
  "v_mul_f32 v91, v47, " UPS "\n\t" \
  "v_add_f32 v52, v84, v89\n\t" \
  "v_fmac_f32 v52, %[m3], v85\n\t" \
  "v_add_f32 v53, v85, v92\n\t" \
  "v_fmac_f32 v53, %[m5], v86\n\t" \
  "v_add_f32 v54, v86, v93\n\t" \
  "v_fmac_f32 v54, %[m7], v87\n\t" \
  "v_add_f32 v55, v87, v91\n\t" \
  "v_fmac_f32 v55, %[m8], v46\n\t"

#define STEPB(PB,PBH,PBP,P13,P57,W,FILLS) W \
  "v_pk_add_f32 v[80:81], " P13 ", v[40:41]\n\t" \
  "v_pk_add_f32 v[82:83], " P57 ", v[40:41]\n\t" \
  "v_add_f32 " PB ", 0x33d6bf95, " PB "\n\t" \
  "v_mov_b32 " PBH ", " PB "\n\t" \
  BCORE(PB,PBP,"v37") FILLS
#define STEPBA(PB,PBH,PBP,P13,P57,W,FILLS) W \
  "v_pk_fma_f32 v[80:81], " P13 ", v[42:43], v[44:45]\n\t" \
  "v_pk_fma_f32 v[82:83], " P57 ", v[42:43], v[44:45]\n\t" \
  "v_fma_f32 " PB ", " PB ", v42, v44\n\t" \
  "v_mov_b32 " PBH ", " PB "\n\t" \
  BCORE(PB,PBP,"v38") \
  "v_mov_b32 v37, v38\n\t" \
  FILLS

// ---- FULL boundary (sentinel logic, in-place rescale, fold reset) ----
#define BDY_FULL(DPPDIR) \
  "v_max3_f32 v80, v48, v49, v50\n\t" \
  "v_max3_f32 v81, v51, v52, v53\n\t" \
  "v_max3_f32 v82, v54, v55, v46\n\t" \
  "v_max3_f32 v90, v80, v81, v82\n\t" \
  "v_cmp_ne_u32 vcc, 0, v90\n\t" \
  "v_lshrrev_b32 v91, 23, v90\n\t" \
  "v_sub_u32 v92, 0xfe, v91\n\t" \
  "v_lshlrev_b32 v92, 23, v92\n\t" \
  "v_cndmask_b32 v92, 1.0, v92, vcc\n\t" \
  "v_mov_b32 v93, v92\n\t" \
  "v_pk_mul_f32 v[48:49], v[48:49], v[92:93]\n\t" \
  "v_pk_mul_f32 v[50:51], v[50:51], v[92:93]\n\t" \
  "v_pk_mul_f32 v[52:53], v[52:53], v[92:93]\n\t" \
  "v_pk_mul_f32 v[54:55], v[54:55], v[92:93]\n\t" \
  "v_mul_f32 v46, v46, v92\n\t" \
  "v_add_u32 v91, 0xffffff81, v91\n\t" \
  "v_add_u32 v91, v30, v91\n\t" \
  "v_mov_b32 v93, 0xf0000000\n\t" \
  "v_cndmask_b32 v30, v93, v91, vcc\n\t" \
  "v_mov_b32 v94, 0xf0000000\n\t" \
  "s_nop 1\n\t" \
  "v_mov_b32_dpp v94, v30 " DPPDIR " row_mask:0xf bank_mask:0xf\n\t" \
  "v_cmp_ne_u32 vcc, 0xf0000000, v30\n\t" \
  "v_cndmask_b32 v30, v94, v30, vcc\n\t" \
  "v_sub_u32 v95, v94, v30\n\t" \
  "v_max_i32 v95, 0xffffff82, v95\n\t" \
  "v_min_i32 v95, 0x78, v95\n\t" \
  "v_add_u32 v95, 0x7f, v95\n\t" \
  "v_lshlrev_b32 v37, 23, v95\n\t" \
  "v_mov_b32 v42, 1.0\n\t" \
  "v_mov_b32 v43, 1.0\n\t" \
  "v_mov_b32 v44, 0x33d6bf95\n\t" \
  "v_mov_b32 v45, 0x33d6bf95\n\t" \
  "v_mov_b32 v38, v37\n\t"
#define BDYF_FULL BDY_FULL("wave_shr:1")
#define BDYB_FULL BDY_FULL("wave_shl:1")

// ---- FAST boundary (post-frontier: no sentinel, fold into next step) ----
#define BDY_FAST(DPPDIR) \
  "v_max3_f32 v80, v48, v49, v50\n\t" \
  "v_max3_f32 v81, v51, v52, v53\n\t" \
  "v_max3_f32 v82, v54, v55, v46\n\t" \
  "v_max3_f32 v90, v80, v81, v82\n\t" \
  "v_lshrrev_b32 v91, 23, v90\n\t" \
  "v_add_u32 v92, 0xffffff81, v91\n\t" \
  "v_add_u32 v30, v30, v92\n\t" \
  "v_sub_u32 v93, 0xfe, v91\n\t" \
  "v_lshlrev_b32 v42, 23, v93\n\t" \
  "v_mov_b32 v43, v42\n\t" \
  "v_mul_f32 v44, 0x33d6bf95, v42\n\t" \
  "v_mov_b32 v45, v44\n\t" \
  "v_mov_b32_dpp v94, v30 " DPPDIR " row_mask:0xf bank_mask:0xf\n\t" \
  "v_sub_u32 v95, v94, v30\n\t" \
  "v_max_i32 v95, 0xffffff82, v95\n\t" \
  "v_min_i32 v95, 0x78, v95\n\t" \
  "v_add_u32 v95, 0x7f, v95\n\t" \
  "v_lshlrev_b32 v38, 23, v95\n\t"
#define BDYF_FAST BDY_FAST("wave_shr:1")
#define BDYB_FAST BDY_FAST("wave_shl:1")

// ---- forward quads ----
#define FQ1(BDY) \
  STEPFA("v96","v97","v[96:97]","v[64:65]","v[66:67]",WLG(10),FILLC("v96","v64","v65","v66","v67",2048)) \
  STEPF("v98","v99","v[98:99]","v[68:69]","v[70:71]",NW,FILLC("v98","v68","v69","v70","v71",2560)) \
  STEPF("v100","v101","v[100:101]","v[72:73]","v[74:75]",WLG(10),FILLC("v100","v72","v73","v74","v75",3072)) \
  STEPF("v102","v103","v[102:103]","v[76:77]","v[78:79]",NW,FILLC("v102","v76","v77","v78","v79",3584)) \
  BDY
#define FQ2(BDY) \
  STEPFA("v96","v97","v[96:97]","v[64:65]","v[66:67]",WLG(10),FILLC("v96","v64","v65","v66","v67",4096)) \
  STEPF("v98","v99","v[98:99]","v[68:69]","v[70:71]",NW,FILLC("v98","v68","v69","v70","v71",4608)) \
  STEPF("v100","v101","v[100:101]","v[72:73]","v[74:75]",WLG(10),FILLC("v100","v72","v73","v74","v75",5120)) \
  STEPF("v102","v103","v[102:103]","v[76:77]","v[78:79]",NW,FILLC("v102","v76","v77","v78","v79",5632)) \
  BDY
#define FQ3(BDY) \
  STEPFA("v96","v97","v[96:97]","v[64:65]","v[66:67]",WLG(10),FILLC("v96","v64","v65","v66","v67",6144)) \
  STEPF("v98","v99","v[98:99]","v[68:69]","v[70:71]",NW,FILLC("v98","v68","v69","v70","v71",6656)) \
  STEPF("v100","v101","v[100:101]","v[72:73]","v[74:75]",WLG(10),FILLC("v100","v72","v73","v74","v75",7168)) \
  STEPF("v102","v103","v[102:103]","v[76:77]","v[78:79]",NW,FILLC("v102","v76","v77","v78","v79",7680)) \
  BDY
#define FQ4(BDY) \
  STEPFA("v96","v97","v[96:97]","v[64:65]","v[66:67]",WLG(10),FILLN("v96","v64","v65","v66","v67",0)) \
  STEPF("v98","v99","v[98:99]","v[68:69]","v[70:71]",NW,FILLN("v98","v68","v69","v70","v71",512)) \
  STEPF("v100","v101","v[100:101]","v[72:73]","v[74:75]",WLG(10),FILLN("v100","v72","v73","v74","v75",1024)) \
  STEPF("v102","v103","v[102:103]","v[76:77]","v[78:79]",NW,FILLN("v102","v76","v77","v78","v79",1536)) \
  BDY

#define FWD_FULL_BODY FQ1(BDYF_FULL) FQ2(BDYF_FULL) FQ3(BDYF_FULL) FQ4(BDYF_FULL)
#define FWD_FAST_BODY FQ1(BDYF_FAST) FQ2(BDYF_FAST) FQ3(BDYF_FAST) FQ4(BDYF_FAST)
#define FWD_FIRST_BODY \
  FILLC("v98","v68","v69","v70","v71",512) \
  FILLC("v100","v72","v73","v74","v75",1024) \
  FILLC("v102","v76","v77","v78","v79",1536) \
  FILLC("v96","v64","v65","v66","v67",2048) \
  STEPFA("v98","v99","v[98:99]","v[68:69]","v[70:71]",WLG(10),FILLC("v98","v68","v69","v70","v71",2560)) \
  STEPF("v100","v101","v[100:101]","v[72:73]","v[74:75]",NW,FILLC("v100","v72","v73","v74","v75",3072)) \
  STEPF("v102","v103","v[102:103]","v[76:77]","v[78:79]",WLG(10),FILLC("v102","v76","v77","v78","v79",3584)) \
  BDYF_FULL \
  FQ2(BDYF_FULL) FQ3(BDYF_FULL) FQ4(BDYF_FULL)
#define FWD_LAST_BODY FQ1(BDYF_FAST) FQ2(BDYF_FAST) FQ3(BDYF_FAST) \
  STEPFA("v96","v97","v[96:97]","v[64:65]","v[66:67]",WLG(10),"") \
  STEPF("v98","v99","v[98:99]","v[68:69]","v[70:71]",NW,"") \
  STEPF("v100","v101","v[100:101]","v[72:73]","v[74:75]",WLG(5),"") \
  STEPF("v102","v103","v[102:103]","v[76:77]","v[78:79]",WLG(0),"") \
  BDYF_FULL

// ---- backward quads ----
#define BQ1(BDY) \
  STEPBA("v96","v97","v[96:97]","v[64:65]","v[66:67]",WLG(10),FILLC("v96","v64","v65","v66","v67",5632)) \
  STEPB("v98","v99","v[98:99]","v[68:69]","v[70:71]",NW,FILLC("v98","v68","v69","v70","v71",5120)) \
  STEPB("v100","v101","v[100:101]","v[72:73]","v[74:75]",WLG(10),FILLC("v100","v72","v73","v74","v75",4608)) \
  STEPB("v102","v103","v[102:103]","v[76:77]","v[78:79]",NW,FILLC("v102","v76","v77","v78","v79",4096)) \
  BDY
#define BQ2(BDY) \
  STEPBA("v96","v97","v[96:97]","v[64:65]","v[66:67]",WLG(10),FILLC("v96","v64","v65","v66","v67",3584)) \
  STEPB("v98","v99","v[98:99]","v[68:69]","v[70:71]",NW,FILLC("v98","v68","v69","v70","v71",3072)) \
  STEPB("v100","v101","v[100:101]","v[72:73]","v[74:75]",WLG(10),FILLC("v100","v72","v73","v74","v75",2560)) \
  STEPB("v102","v103","v[102:103]","v[76:77]","v[78:79]",NW,FILLC("v102","v76","v77","v78","v79",2048)) \
  BDY
#define BQ3(BDY) \
  STEPBA("v96","v97","v[96:97]","v[64:65]","v[66:67]",WLG(10),FILLC("v96","v64","v65","v66","v67",1536)) \
  STEPB("v98","v99","v[98:99]","v[68:69]","v[70:71]",NW,FILLC("v98","v68","v69","v70","v71",1024)) \
  STEPB("v100","v101","v[100:101]","v[72:73]","v[74:75]",WLG(10),FILLC("v100","v72","v73","v74","v75",512)) \
  STEPB("v102","v103","v[102:103]","v[76:77]","v[78:79]",NW,FILLC("v102","v76","v77","v78","v79",0)) \
  BDY
#define BQ4(BDY) \
  STEPBA("v96","v97","v[96:97]","v[64:65]","v[66:67]",WLG(10),FILLN("v96","v64","v65","v66","v67",7680)) \
  STEPB("v98","v99","v[98:99]","v[68:69]","v[70:71]",NW,FILLN("v98","v68","v69","v70","v71",7168)) \
  STEPB("v100","v101","v[100:101]","v[72:73]","v[74:75]",WLG(10),FILLN("v100","v72","v73","v74","v75",6656)) \
  STEPB("v102","v103","v[102:103]","v[76:77]","v[78:79]",NW,FILLN("v102","v76","v77","v78","v79",6144)) \
  BDY

#define BWD_FULL_BODY BQ1(BDYB_FULL) BQ2(BDYB_FULL) BQ3(BDYB_FULL) BQ4(BDYB_FULL)
#define BWD_FAST_BODY BQ1(BDYB_FAST) BQ2(BDYB_FAST) BQ3(BDYB_FAST) BQ4(BDYB_FAST)
#define BWD_FIRST_BODY \
  FILLC("v96","v64","v65","v66","v67",7680) \
  FILLC("v98","v68","v69","v70","v71",7168) \
  FILLC("v100","v72","v73","v74","v75",6656) \
  FILLC("v102","v76","v77","v78","v79",6144) \
  BWD_FULL_BODY
#define BWD_LAST_BODY BQ1(BDYB_FAST) BQ2(BDYB_FAST) BQ3(BDYB_FAST) \
  STEPBA("v96","v97","v[96:97]","v[64:65]","v[66:67]",WLG(10),"") \
  STEPB("v98","v99","v[98:99]","v[68:69]","v[70:71]",NW,"") \
  STEPB("v100","v101","v[100:101]","v[72:73]","v[74:75]",WLG(5),"") \
  STEPB("v102","v103","v[102:103]","v[76:77]","v[78:79]",WLG(0),"") \
  BDYB_FULL

// ---- pinned operands (explicit physical registers) ----
#define ST_OUTS \
  [x02l]"+{v48}"(x02l),[x02h]"+{v49}"(x02h),[x46l]"+{v50}"(x46l),[x46h]"+{v51}"(x46h), \
  [o13l]"+{v52}"(o13l),[o13h]"+{v53}"(o13h),[o57l]"+{v54}"(o57l),[o57h]"+{v55}"(o57h), \
  [a8]"+{v46}"(a8v),[z0]"+{v47}"(z0v),[E]"+{v30}"(Ev), \
  [ups]"+{v37}"(upsv),[upn]"+{v38}"(upnv), \
  [epl]"+{v40}"(eplv),[eph]"+{v41}"(ephv), \
  [scl]"+{v42}"(sclv),[sch]"+{v43}"(schv),[escl]"+{v44}"(esclv),[esch]"+{v45}"(eschv), \
  [pb0]"+{v96}"(pb0),[pb1]"+{v98}"(pb1),[pb2]"+{v100}"(pb2),[pb3]"+{v102}"(pb3), \
  [qa0]"+{v64}"(qa0),[qb0]"+{v65}"(qb0),[qc0]"+{v66}"(qc0),[qd0]"+{v67}"(qd0), \
  [qa1]"+{v68}"(qa1),[qb1]"+{v69}"(qb1),[qc1]"+{v70}"(qc1),[qd1]"+{v71}"(qd1), \
  [qa2]"+{v72}"(qa2),[qb2]"+{v73}"(qb2),[qc2]"+{v74}"(qc2),[qd2]"+{v75}"(qd2), \
  [qa3]"+{v76}"(qa3),[qb3]"+{v77}"(qb3),[qc3]"+{v78}"(qc3),[qd3]"+{v79}"(qd3)

#define SCLOBS "vcc","memory", \
  "v80","v81","v82","v83","v84","v85","v86","v87","v88","v89", \
  "v90","v91","v92","v93","v94","v95","v97","v99","v101","v103"

#define RUN_CHUNK(BODY, XB,X1,X3,X5,X7, YB,Y1,Y3,Y5,Y7) \
  asm volatile(BODY : ST_OUTS \
    : [m1]"v"(m1f),[m3]"v"(m3f),[m5]"v"(m5f),[m7]"v"(m7f),[m8]"v"(m8f), \
      [cB]"v"(XB),[c1]"v"(X1),[c3]"v"(X3),[c5]"v"(X5),[c7]"v"(X7), \
      [nB]"v"(YB),[n1]"v"(Y1),[n3]"v"(Y3),[n5]"v"(Y5),[n7]"v"(Y7) \
    : SCLOBS)

#define RUN_BDY(BODY) \
  asm volatile(BODY : ST_OUTS \
    : [m1]"v"(m1f),[m3]"v"(m3f),[m5]"v"(m5f),[m7]"v"(m7f),[m8]"v"(m8f) \
    : SCLOBS)

__launch_bounds__(128, 1)
__global__ void ctc_loss_kernel(const int* __restrict__ y_true,
                                const float* __restrict__ y_pred,
                                float* __restrict__ out) {
    const int b = blockIdx.x;
    const int tid = threadIdx.x;
    const int w = __builtin_amdgcn_readfirstlane(tid >> 6);  // 0=fwd, 1=bwd
    const int l = tid & 63;

    __shared__ float ring[2][4][CH_ * C_];  // 2 waves x 4 bufs x 16x128 = 64 KB

    const int* __restrict__ lab = y_true + b * L_;
    const int4 lv = *(const int4*)(lab + 4 * l);
    const int e1 = lv.x, e3 = lv.y, e5 = lv.z, e7 = lv.w;
    const int em1 = (l > 0) ? lab[4 * l - 1] : -1;
    const float m1f = ((l > 0) && (e1 != em1)) ? 1.0f : 0.0f;
    const float m3f = (e3 != e1) ? 1.0f : 0.0f;
    const float m5f = (e5 != e3) ? 1.0f : 0.0f;
    const float m7f = (e7 != e5) ? 1.0f : 0.0f;
    const float m8f = (l == 63) ? 1.0f : 0.0f;

    const float* __restrict__ base = y_pred + (size_t)b * (T_ * C_);

    lds_f* lb = (lds_f*)&ring[0][0][0];
    lds_f* q0 = lb + w * 8192;
    lds_f* q1 = q0 + 2048;
    lds_f* q2 = q0 + 4096;
    lds_f* q3 = q0 + 6144;
    lds_f *cB0 = q0 + BLANK_, *c10 = q0 + e1, *c30 = q0 + e3,
          *c50 = q0 + e5, *c70 = q0 + e7;
    lds_f *cB1 = q1 + BLANK_, *c11 = q1 + e1, *c31 = q1 + e3,
          *c51 = q1 + e5, *c71 = q1 + e7;
    lds_f *cB2 = q2 + BLANK_, *c12 = q2 + e1, *c32 = q2 + e3,
          *c52 = q2 + e5, *c72 = q2 + e7;
    lds_f *cB3 = q3 + BLANK_, *c13 = q3 + e1, *c33 = q3 + e3,
          *c53 = q3 + e5, *c73 = q3 + e7;

    auto issueF = [&](int c, int buf) {
        const float* g = base + (size_t)c * CH_ * C_ + 4 * l;
#pragma unroll
        for (int i = 0; i < 8; ++i)
            gl2lds16(g + i * 256, &ring[0][buf][i * 256]);
    };
    auto issueB = [&](int qc, int buf) {
        const float* g = base + (size_t)(127 - qc) * CH_ * C_ + 4 * l;
#pragma unroll
        for (int i = 0; i < 8; ++i)
            gl2lds16(g + i * 256, &ring[1][buf][i * 256]);
    };

    // pinned state/lookahead variables (see register map in ST_OUTS)
    float x02l = 0.f, x02h = 0.f, x46l = 0.f, x46h = 0.f,
          o13l = 0.f, o13h = 0.f, o57l = 0.f, o57h = 0.f, a8v = 0.f;
    int Ev = SENT_;
    float upsv = 1.0f, upnv = 1.0f, z0v = 0.0f;
    float sclv = 1.0f, schv = 1.0f, esclv = EPSF, eschv = EPSF,
          eplv = EPSF, ephv = EPSF;
    float pb0 = 0.f, pb1 = 0.f, pb2 = 0.f, pb3 = 0.f;
    float qa0 = 0.f, qb0 = 0.f, qc0 = 0.f, qd0 = 0.f,
          qa1 = 0.f, qb1 = 0.f, qc1 = 0.f, qd1 = 0.f,
          qa2 = 0.f, qb2 = 0.f, qc2 = 0.f, qd2 = 0.f,
          qa3 = 0.f, qb3 = 0.f, qc3 = 0.f, qd3 = 0.f;

    if (w == 0) {
        // ======== forward: chunks 0..63 (t = 0..1023) ========
        issueF(0, 0); issueF(1, 1); issueF(2, 2);
        WAIT_VM(8);
        issueF(3, 3);
        {
            const float* rbf = &ring[0][0][0];
            const float i0 = rbf[BLANK_] + EPSF;
            const float i1 = rbf[e1] + EPSF;
            if (l == 0) { x02l = i0; o13l = i1; Ev = 0; }
        }
        RUN_BDY(BDYF_FULL);
        DRAIN_LGKM();
        RUN_CHUNK(FWD_FIRST_BODY, cB0,c10,c30,c50,c70, cB1,c11,c31,c51,c71);
        WAIT_VM(8); issueF(4, 0);
        RUN_CHUNK(FWD_FULL_BODY, cB1,c11,c31,c51,c71, cB2,c12,c32,c52,c72);
        WAIT_VM(8); issueF(5, 1);
        RUN_CHUNK(FWD_FULL_BODY, cB2,c12,c32,c52,c72, cB3,c13,c33,c53,c73);
        WAIT_VM(8); issueF(6, 2);
        RUN_CHUNK(FWD_FULL_BODY, cB3,c13,c33,c53,c73, cB0,c10,c30,c50,c70);
#pragma unroll 1
        for (int m = 1; m <= 6; ++m) {     // chunks 4..27 (frontier region)
            WAIT_VM(8); issueF(4 * m + 3, 3);
            RUN_CHUNK(FWD_FULL_BODY, cB0,c10,c30,c50,c70, cB1,c11,c31,c51,c71);
            WAIT_VM(8); issueF(4 * m + 4, 0);
            RUN_CHUNK(FWD_FULL_BODY, cB1,c11,c31,c51,c71, cB2,c12,c32,c52,c72);
            WAIT_VM(8); issueF(4 * m + 5, 1);
            RUN_CHUNK(FWD_FULL_BODY, cB2,c12,c32,c52,c72, cB3,c13,c33,c53,c73);
            WAIT_VM(8); issueF(4 * m + 6, 2);
            RUN_CHUNK(FWD_FULL_BODY, cB3,c13,c33,c53,c73, cB0,c10,c30,c50,c70);
        }
#pragma unroll 1
        for (int m = 7; m <= 14; ++m) {    // chunks 28..59 (fast region)
            WAIT_VM(8); issueF(4 * m + 3, 3);
            RUN_CHUNK(FWD_FAST_BODY, cB0,c10,c30,c50,c70, cB1,c11,c31,c51,c71);
            WAIT_VM(8); issueF(4 * m + 4, 0);
            RUN_CHUNK(FWD_FAST_BODY, cB1,c11,c31,c51,c71, cB2,c12,c32,c52,c72);
            WAIT_VM(8); issueF(4 * m + 5, 1);
            RUN_CHUNK(FWD_FAST_BODY, cB2,c12,c32,c52,c72, cB3,c13,c33,c53,c73);
            WAIT_VM(8); issueF(4 * m + 6, 2);
            RUN_CHUNK(FWD_FAST_BODY, cB3,c13,c33,c53,c73, cB0,c10,c30,c50,c70);
        }
        WAIT_VM(8); issueF(63, 3);
        RUN_CHUNK(FWD_FAST_BODY, cB0,c10,c30,c50,c70, cB1,c11,c31,c51,c71);
        WAIT_VM(8);
        RUN_CHUNK(FWD_FAST_BODY, cB1,c11,c31,c51,c71, cB2,c12,c32,c52,c72);
        WAIT_VM(0);
        RUN_CHUNK(FWD_FAST_BODY, cB2,c12,c32,c52,c72, cB3,c13,c33,c53,c73);
        RUN_CHUNK(FWD_LAST_BODY, cB3,c13,c33,c53,c73, cB3,c13,c33,c53,c73);
    } else {
        // ======== backward: t = 2047..1024 (qc = 0..63) ========
        issueB(0, 0); issueB(1, 1); issueB(2, 2);
        WAIT_VM(8);
        issueB(3, 3);
        if (l == 63) { o57h = 1.0f; a8v = 1.0f; Ev = 0; }  // c_2048 = f
        RUN_BDY(BDYB_FULL);
        DRAIN_LGKM();
        RUN_CHUNK(BWD_FIRST_BODY, cB0,c10,c30,c50,c70, cB1,c11,c31,c51,c71);
        WAIT_VM(8); issueB(4, 0);
        RUN_CHUNK(BWD_FULL_BODY, cB1,c11,c31,c51,c71, cB2,c12,c32,c52,c72);
        WAIT_VM(8); issueB(5, 1);
        RUN_CHUNK(BWD_FULL_BODY, cB2,c12,c32,c52,c72, cB3,c13,c33,c53,c73);
        WAIT_VM(8); issueB(6, 2);
        RUN_CHUNK(BWD_FULL_BODY, cB3,c13,c33,c53,c73, cB0,c10,c30,c50,c70);
#pragma unroll 1
        for (int m = 1; m <= 6; ++m) {
            WAIT_VM(8); issueB(4 * m + 3, 3);
            RUN_CHUNK(BWD_FULL_BODY, cB0,c10,c30,c50,c70, cB1,c11,c31,c51,c71);
            WAIT_VM(8); issueB(4 * m + 4, 0);
            RUN_CHUNK(BWD_FULL_BODY, cB1,c11,c31,c51,c71, cB2,c12,c32,c52,c72);
            WAIT_VM(8); issueB(4 * m + 5, 1);
            RUN_CHUNK(BWD_FULL_BODY, cB2,c12,c32,c52,c72, cB3,c13,c33,c53,c73);
            WAIT_VM(8); issueB(4 * m + 6, 2);
            RUN_CHUNK(BWD_FULL_BODY, cB3,c13,c33,c53,c73, cB0,c10,c30,c50,c70);
        }
#pragma unroll 1
        for (int m = 7; m <= 14; ++m) {
            WAIT_VM(8); issueB(4 * m + 3, 3);
            RUN_CHUNK(BWD_FAST_BODY, cB0,c10,c30,c50,c70, cB1,c11,c31,c51,c71);
            WAIT_VM(8); issueB(4 * m + 4, 0);
            RUN_CHUNK(BWD_FAST_BODY, cB1,c11,c31,c51,c71, cB2,c12,c32,c52,c72);
            WAIT_VM(8); issueB(4 * m + 5, 1);
            RUN_CHUNK(BWD_FAST_BODY, cB2,c12,c32,c52,c72, cB3,c13,c33,c53,c73);
            WAIT_VM(8); issueB(4 * m + 6, 2);
            RUN_CHUNK(BWD_FAST_BODY, cB3,c13,c33,c53,c73, cB0,c10,c30,c50,c70);
        }
        WAIT_VM(8); issueB(63, 3);
        RUN_CHUNK(BWD_FAST_BODY, cB0,c10,c30,c50,c70, cB1,c11,c31,c51,c71);
        WAIT_VM(8);
        RUN_CHUNK(BWD_FAST_BODY, cB1,c11,c31,c51,c71, cB2,c12,c32,c52,c72);
        WAIT_VM(0);
        RUN_CHUNK(BWD_FAST_BODY, cB2,c12,c32,c52,c72, cB3,c13,c33,c53,c73);
        RUN_CHUNK(BWD_LAST_BODY, cB3,c13,c33,c53,c73, cB3,c13,c33,c53,c73);
        // export c_{1024}; state order (a0..a8) =
        // x02l,o13l,x02h,o13h,x46l,o57l,x46h,o57h,a8
        float* xf = &ring[1][0][0];
        xf[0 * 64 + l] = x02l; xf[1 * 64 + l] = o13l; xf[2 * 64 + l] = x02h;
        xf[3 * 64 + l] = o13h; xf[4 * 64 + l] = x46l; xf[5 * 64 + l] = o57l;
        xf[6 * 64 + l] = x46h; xf[7 * 64 + l] = o57h; xf[8 * 64 + l] = a8v;
        ((int*)xf)[9 * 64 + l] = Ev;
    }

    __syncthreads();

    if (w == 0) {
        // p = <alpha_{1023}, c_{1024}>: lane dot then 64-lane logsumexp.
        const float* xf = &ring[1][0][0];
        float sd = x02l * xf[0 * 64 + l];
        sd = fmaf(o13l, xf[1 * 64 + l], sd);
        sd = fmaf(x02h, xf[2 * 64 + l], sd);
        sd = fmaf(o13h, xf[3 * 64 + l], sd);
        sd = fmaf(x46l, xf[4 * 64 + l], sd);
        sd = fmaf(o57l, xf[5 * 64 + l], sd);
        sd = fmaf(x46h, xf[6 * 64 + l], sd);
        sd = fmaf(o57h, xf[7 * 64 + l], sd);
        sd = fmaf(a8v, xf[8 * 64 + l], sd);
        const int E2 = ((const int*)xf)[9 * 64 + l];
        const bool nz = (sd > 0.0f);
        int Es = nz ? (Ev + E2) : SENT_;
        int M = Es;
#pragma unroll
        for (int o = 32; o; o >>= 1) M = max(M, __shfl_xor(M, o));
        int d = Es - M;
        d = max(d, -126);
        float val = nz ? sd * __uint_as_float((unsigned)(d + 127) << 23) : 0.0f;
#pragma unroll
        for (int o = 32; o; o >>= 1) val += __shfl_xor(val, o);
        if (l == 0) out[b] = -(__logf(val) + (float)M * LN2F);
    }
}

extern "C" void kernel_launch(void* const* d_in, const int* in_sizes, int n_in,
                              void* d_out, int out_size, void* d_ws, size_t ws_size,
                              hipStream_t stream) {
    const int* y_true = (const int*)d_in[0];
    const float* y_pred = (const float*)d_in[1];
    float* out = (float*)d_out;
    ctc_loss_kernel<<<B_, 64 * 2, 0, stream>>>(y_true, y_pred, out);
}